// Round 18
// baseline (1524.178 us; speedup 1.0000x reference)
//
#include <hip/hip_runtime.h>

typedef unsigned short u16;
typedef __attribute__((ext_vector_type(8))) short     bf16x8;
typedef __attribute__((ext_vector_type(8))) unsigned short u16x8;
typedef __attribute__((ext_vector_type(4))) unsigned short u16x4;
typedef __attribute__((ext_vector_type(4))) float     f32x4;

#define GADDR(p) ((const __attribute__((address_space(1))) void*)(p))
#define LADDR(p) ((__attribute__((address_space(3))) void*)(p))

__device__ __forceinline__ u16 f2bf(float f) {
  unsigned u = __float_as_uint(f);
  u += 0x7fffu + ((u >> 16) & 1u);           // round-to-nearest-even
  return (u16)(u >> 16);
}
__device__ __forceinline__ float bf2f(u16 h) {
  return __uint_as_float(((unsigned)h) << 16);
}

// ---------------------------------------------------------------------------
__global__ void wt_kernel(const float* __restrict__ w, u16* __restrict__ wt,
                          int K, int N) {
  size_t idx = (size_t)blockIdx.x * 256 + threadIdx.x;
  if (idx >= (size_t)K * N) return;
  int n = (int)(idx / K);
  int k = (int)(idx % K);
  wt[idx] = f2bf(w[(size_t)k * N + n]);
}

// ---------------------------------------------------------------------------
__global__ __launch_bounds__(64)
void bias_kernel(const float* __restrict__ w1, const float* __restrict__ b1,
                 const float* __restrict__ w2, const float* __restrict__ b2,
                 float* __restrict__ out) {
  const int p = blockIdx.x;            // 0..4095  = i*64 + j
  const int i = p >> 6, j = p & 63;
  const float d0 = (float)((i >> 3) - (j >> 3));
  const float d1 = (float)((i & 7) - (j & 7));
  const float r0 = copysignf(log1pf(fabsf(d0)), d0);
  const float r1 = copysignf(log1pf(fabsf(d1)), d1);
  float part[16];
#pragma unroll
  for (int h = 0; h < 16; ++h) part[h] = 0.f;
  for (int m = threadIdx.x; m < 384; m += 64) {
    float hv = fmaxf(r0 * w1[m] + r1 * w1[384 + m] + b1[m], 0.f);
#pragma unroll
    for (int h = 0; h < 16; ++h) part[h] += hv * w2[m * 16 + h];
  }
#pragma unroll
  for (int h = 0; h < 16; ++h) {
    float v = part[h];
#pragma unroll
    for (int off = 32; off; off >>= 1) v += __shfl_xor(v, off);
    if (threadIdx.x == 0) out[(size_t)h * 4096 + p] = v + b2[h];
  }
}

// ---------------------------------------------------------------------------
__global__ __launch_bounds__(64)
void bias2_kernel(const float* __restrict__ bb, float* __restrict__ b2) {
  const int blk = blockIdx.x;          // h*16 + mi*4 + ni
  const int h = blk >> 4, mi = (blk >> 2) & 3, ni = blk & 3;
  const int lane = threadIdx.x, fr = lane & 15, fq = lane >> 4;
  float4 o;
  o.x = bb[(size_t)h * 4096 + (mi * 16 + fq * 4 + 0) * 64 + ni * 16 + fr];
  o.y = bb[(size_t)h * 4096 + (mi * 16 + fq * 4 + 1) * 64 + ni * 16 + fr];
  o.z = bb[(size_t)h * 4096 + (mi * 16 + fq * 4 + 2) * 64 + ni * 16 + fr];
  o.w = bb[(size_t)h * 4096 + (mi * 16 + fq * 4 + 3) * 64 + ni * 16 + fr];
  ((float4*)b2)[(size_t)blk * 64 + lane] = o;
}

// ---------------------------------------------------------------------------
__global__ __launch_bounds__(128)
void partition_kernel(const float* __restrict__ x, u16* __restrict__ xw) {
  const size_t r = blockIdx.x;
  const int w   = (int)(r >> 6);
  const int i   = (int)(r & 63);
  const int b   = w >> 6;
  const int win = w & 63;
  const int hs = (((win >> 3) << 3) + (i >> 3) + 4) & 63;
  const int ws2 = (((win & 7) << 3) + (i & 7) + 4) & 63;
  const float4* src = (const float4*)(x + (((size_t)b << 12) + hs * 64 + ws2) * 512);
  u16* dst = xw + r * 512;
  const int t = threadIdx.x;
  float4 v = src[t];
  u16x4 o;
  o[0] = f2bf(v.x); o[1] = f2bf(v.y); o[2] = f2bf(v.z); o[3] = f2bf(v.w);
  *(u16x4*)(dst + t * 4) = o;
}

// ---------------------------------------------------------------------------
// 256x256 tile, BK=64, 8 waves (2Mx4N), TWO-phase schedule (merged from 4:
// round 17 showed 9 barriers/tile dominated at NT=8). P0': all 16 A-frags +
// B nh0 -> 32 MFMA; P1': B nh1 -> 32 MFMA. 5 barriers/tile.
// Stage ledger: P0' stages {A,B}(s+1,h1)->NSLOT (reads drained end of s-1);
// P1' stages {A,B}(s+2,h0)->SLOT (reads drained by P0' lgkm+barrier).
// Boundary vmcnt(4) steady / vmcnt(0) tail. K-loop unrolled x2 (compile-time
// slot). MODE 0: bf16 out, 2: bf16 + tanh-GELU.
// ---------------------------------------------------------------------------
template <int MODE>
__global__ __launch_bounds__(512, 1)
void gemm8(const u16* __restrict__ A, const u16* __restrict__ Wt,
           const float* __restrict__ bias, void* __restrict__ outp,
           int M, int N, int K) {
  __shared__ u16 lds[65536];           // 2 slots x 64 KiB
  const int t = threadIdx.x;           // 0..511
  const int gx = gridDim.x;            // N/256
  const int nwg = gx * gridDim.y;
  const int wg = blockIdx.y * gx + blockIdx.x;
  const int swzb = (wg & 7) * (nwg >> 3) + (wg >> 3);  // bijective: nwg%8==0
  const int n0 = (swzb % gx) * 256;
  const int m0 = (swzb / gx) * 256;

  const int lane = t & 63;
  const int wid = t >> 6;
  const int wr = (wid >> 2) * 128;
  const int wc = (wid & 3) * 64;
  const int fr = lane & 15, fq = lane >> 4;
  const int c0 = (fq ^ (fr & 7)) * 8;        // swizzled chunk slot, kk=0
  const int c1 = ((4 + fq) ^ (fr & 7)) * 8;  // kk=1

  const int tq = t >> 3;
  const int scol = ((t & 7) ^ (tq & 7)) * 8;
  const u16* Asrc = A  + (size_t)(m0 + tq) * K + scol;
  const int rowB = (tq & 31) + ((t >> 8) << 6);
  const u16* Bsrc = Wt + (size_t)(n0 + rowB) * K + scol;
  const int dA = t * 8;
  const int dB = 16384 + ((t >> 8) << 11) + t * 8;

#define SG_A(slot, src, h) do {                                               \
    const int _d = (slot) * 32768 + (h) * 4096 + dA;                          \
    const size_t _k = (size_t)(src) * 64 + (size_t)((h) * 64) * K;            \
    __builtin_amdgcn_global_load_lds(GADDR(Asrc + _k), LADDR(&lds[_d]), 16, 0, 0); \
    __builtin_amdgcn_global_load_lds(GADDR(Asrc + _k + (size_t)128 * K),      \
                                     LADDR(&lds[_d + 8192]), 16, 0, 0);       \
  } while (0)
#define SG_B(slot, src, h) do {                                               \
    const int _d = (slot) * 32768 + (h) * 2048 + dB;                          \
    const size_t _k = (size_t)(src) * 64 + (size_t)((h) * 32) * K;            \
    __builtin_amdgcn_global_load_lds(GADDR(Bsrc + _k), LADDR(&lds[_d]), 16, 0, 0); \
    __builtin_amdgcn_global_load_lds(GADDR(Bsrc + _k + (size_t)128 * K),      \
                                     LADDR(&lds[_d + 8192]), 16, 0, 0);       \
  } while (0)

  f32x4 acc[8][4];
#pragma unroll
  for (int a = 0; a < 8; ++a)
#pragma unroll
    for (int b = 0; b < 4; ++b) acc[a][b] = (f32x4){0.f, 0.f, 0.f, 0.f};

  const int NT = K >> 6;               // BK=64 tiles; NT is even (8 or 32)
  // prologue: tile0 full (8 loads) + tile1 h0 (4 loads); tile1 h1 is staged
  // inside tile0's P0'.
  SG_A(0, 0, 0); SG_A(0, 0, 1); SG_B(0, 0, 0); SG_B(0, 0, 1);
  SG_A(1, 1, 0); SG_B(1, 1, 0);
  asm volatile("s_waitcnt vmcnt(4)" ::: "memory");
  __builtin_amdgcn_s_barrier();

// One K-tile, 2 phases. S runtime index, SLOT/NSLOT compile-time 0/1.
// C1 = (S+1 < NT), C2 = (S+2 < NT).
#define TILE_BODY(S, SLOT, NSLOT, C1, C2)                                     \
  {                                                                           \
    const u16* la = lds + (SLOT) * 32768;                                     \
    const u16* lb = la + 16384;                                               \
    bf16x8 af[16], bf[8];                                                     \
    /* ---- P0': all A frags + B nh0 ---- */                                  \
    _Pragma("unroll")                                                         \
    for (int mi = 0; mi < 8; ++mi) {                                          \
      const int r = (wr + mi * 16 + fr) * 64;                                 \
      af[mi * 2]     = *(const bf16x8*)&la[r + c0];                           \
      af[mi * 2 + 1] = *(const bf16x8*)&la[r + c1];                           \
    }                                                                         \
    _Pragma("unroll")                                                         \
    for (int ni = 0; ni < 2; ++ni) {                                          \
      const int r = (wc + ni * 16 + fr) * 64;                                 \
      bf[ni * 2]     = *(const bf16x8*)&lb[r + c0];                           \
      bf[ni * 2 + 1] = *(const bf16x8*)&lb[r + c1];                           \
    }                                                                         \
    if (C1) { SG_A(NSLOT, (S) + 1, 1); SG_B(NSLOT, (S) + 1, 1); }             \
    __builtin_amdgcn_s_barrier();                                             \
    asm volatile("s_waitcnt lgkmcnt(0)" ::: "memory");                        \
    __builtin_amdgcn_sched_barrier(0);                                        \
    __builtin_amdgcn_s_setprio(1);                                            \
    _Pragma("unroll")                                                         \
    for (int mi = 0; mi < 8; ++mi)                                            \
      _Pragma("unroll")                                                       \
      for (int ni = 0; ni < 2; ++ni) {                                        \
        acc[mi][ni] = __builtin_amdgcn_mfma_f32_16x16x32_bf16(                \
            af[mi * 2], bf[ni * 2], acc[mi][ni], 0, 0, 0);                    \
        acc[mi][ni] = __builtin_amdgcn_mfma_f32_16x16x32_bf16(                \
            af[mi * 2 + 1], bf[ni * 2 + 1], acc[mi][ni], 0, 0, 0);            \
      }                                                                       \
    __builtin_amdgcn_s_setprio(0);                                            \
    __builtin_amdgcn_s_barrier();                                             \
    /* ---- P1': B nh1 ---- */                                                \
    _Pragma("unroll")                                                         \
    for (int ni = 0; ni < 2; ++ni) {                                          \
      const int r = (wc + 32 + ni * 16 + fr) * 64;                            \
      bf[4 + ni * 2]     = *(const bf16x8*)&lb[r + c0];                       \
      bf[4 + ni * 2 + 1] = *(const bf16x8*)&lb[r + c1];                       \
    }                                                                         \
    if (C2) { SG_A(SLOT, (S) + 2, 0); SG_B(SLOT, (S) + 2, 0); }               \
    __builtin_amdgcn_s_barrier();                                             \
    asm volatile("s_waitcnt lgkmcnt(0)" ::: "memory");                        \
    __builtin_amdgcn_sched_barrier(0);                                        \
    __builtin_amdgcn_s_setprio(1);                                            \
    _Pragma("unroll")                                                         \
    for (int mi = 0; mi < 8; ++mi)                                            \
      _Pragma("unroll")                                                       \
      for (int ni = 0; ni < 2; ++ni) {                                        \
        acc[mi][2 + ni] = __builtin_amdgcn_mfma_f32_16x16x32_bf16(            \
            af[mi * 2], bf[4 + ni * 2], acc[mi][2 + ni], 0, 0, 0);            \
        acc[mi][2 + ni] = __builtin_amdgcn_mfma_f32_16x16x32_bf16(            \
            af[mi * 2 + 1], bf[4 + ni * 2 + 1], acc[mi][2 + ni], 0, 0, 0);    \
      }                                                                       \
    __builtin_amdgcn_s_setprio(0);                                            \
    /* boundary: tile S+1 must be fully resident. Steady: 8 outstanding,     \
       newest 4 belong to S+2 -> vmcnt(4). Tail: vmcnt(0). */                 \
    if (C2) asm volatile("s_waitcnt vmcnt(4)" ::: "memory");                  \
    else    asm volatile("s_waitcnt vmcnt(0)" ::: "memory");                  \
    __builtin_amdgcn_s_barrier();                                             \
  }

  for (int s = 0; s < NT; s += 2) {
    TILE_BODY(s,     0, 1, true,          (s + 2 < NT));
    TILE_BODY(s + 1, 1, 0, (s + 2 < NT),  (s + 3 < NT));
  }
#undef TILE_BODY
#undef SG_A
#undef SG_B
  asm volatile("s_waitcnt vmcnt(0)" ::: "memory");  // drain before LDS reuse
  __syncthreads();

  // ---- epilogue: swizzled LDS stage -> coalesced stores ----
  float bv4[4];
#pragma unroll
  for (int ni = 0; ni < 4; ++ni) bv4[ni] = bias[n0 + wc + ni * 16 + fr];

  u16* uW = &lds[wid * 8192];
  u16* og = (u16*)outp;
#pragma unroll
  for (int mi = 0; mi < 8; ++mi) {
#pragma unroll
    for (int ni = 0; ni < 4; ++ni)
#pragma unroll
      for (int j = 0; j < 4; ++j) {
        float v = acc[mi][ni][j] + bv4[ni];
        if (MODE == 2) {               // tanh-approx GELU
          const float a2 = v * (1.5957691216f + 0.0713548162f * v * v);
          const float e = __expf(a2);
          v = v * (e * __builtin_amdgcn_rcpf(e + 1.0f));
        }
        uW[(fq * 4 + j) * 64 + ((ni ^ j ^ fq) & 3) * 16 + fr] = f2bf(v);
      }
#pragma unroll
    for (int p = 0; p < 2; ++p) {
      const int r = p * 8 + (lane >> 3);
      const int sg = (((lane & 7) >> 1) ^ (r & 3) ^ ((r >> 2) & 3)) & 3;
      u16x8 v8 = *(const u16x8*)&uW[r * 64 + sg * 16 + (lane & 1) * 8];
      const int row = m0 + wr + mi * 16 + r;
      *(u16x8*)&og[(size_t)row * N + n0 + wc + (lane & 7) * 8] = v8;
    }
  }
}

// ---------------------------------------------------------------------------
// Fused GEMM(128x512 tile) + residual + LayerNorm, bf16-residual edition.
// LNM 0: A=AO, resid=XW (window layout, row=rowg); writes X1B (token layout).
// LNM 1: A=HBUF, resid=X1B (row=rowg); writes d_out (f32).
// ---------------------------------------------------------------------------
template <int LNM>
__global__ __launch_bounds__(512, 1)
void gemm_ln(const u16* __restrict__ A, const u16* __restrict__ Wt,
             const float* __restrict__ bias, const u16* __restrict__ residb,
             const float* __restrict__ g, const float* __restrict__ bt,
             float* __restrict__ out1, u16* __restrict__ out1b, int K) {
  __shared__ u16 lds[61440];
  const int t = threadIdx.x;
  const int nwg = gridDim.x;
  const int wg = blockIdx.x;
  const int swz = (wg & 7) * (nwg >> 3) + (wg >> 3);   // nwg % 8 == 0
  const int m0 = swz * 128;

  const int lane = t & 63;
  const int wid = t >> 6;
  const int wc = wid * 64;
  const int fr = lane & 15, fq = lane >> 4;
  const int rx = (fr >> 1) & 3;

  const int srow = t >> 2;             // 0..127
  const int schk = ((t & 3) ^ ((srow >> 1) & 3)) * 8;
  const u16* Ag = A  + (size_t)(m0 + srow) * K + schk;
  const u16* Bg = Wt + (size_t)srow * K + schk;

#define GLSTAGE_A(tile, buf)                                                  \
    __builtin_amdgcn_global_load_lds(GADDR(Ag + (size_t)(tile) * 32),         \
        LADDR(&lds[(buf) * 20480 + t * 8]), 16, 0, 0)
#define GLSTAGE_B(tile, buf, p)                                               \
    __builtin_amdgcn_global_load_lds(                                         \
        GADDR(Bg + (size_t)(p) * 128 * K + (size_t)(tile) * 32),              \
        LADDR(&lds[(buf) * 20480 + 4096 + (p) * 4096 + t * 8]), 16, 0, 0)

  f32x4 acc[8][4];
#pragma unroll
  for (int a = 0; a < 8; ++a)
#pragma unroll
    for (int b = 0; b < 4; ++b) acc[a][b] = (f32x4){0.f, 0.f, 0.f, 0.f};

  const int NT = K >> 5;
  GLSTAGE_A(0, 0);
  GLSTAGE_B(0, 0, 0); GLSTAGE_B(0, 0, 1); GLSTAGE_B(0, 0, 2); GLSTAGE_B(0, 0, 3);
  GLSTAGE_A(1, 1);
  GLSTAGE_B(1, 1, 0); GLSTAGE_B(1, 1, 1); GLSTAGE_B(1, 1, 2); GLSTAGE_B(1, 1, 3);

  int cur = 0;
  for (int u = 0; u < NT; ++u) {
    if (u + 1 < NT) asm volatile("s_waitcnt vmcnt(5)" ::: "memory");
    else            asm volatile("s_waitcnt vmcnt(0)" ::: "memory");
    __builtin_amdgcn_s_barrier();

    const u16* lb = lds + cur * 20480;
    const int stg = (cur == 0) ? 2 : cur - 1;   // (cur+2)%3
    bf16x8 bfr[4], af0[4], af1[4];
#pragma unroll
    for (int ni = 0; ni < 4; ++ni)
      bfr[ni] = *(const bf16x8*)&lb[4096 + (wc + ni * 16 + fr) * 32 + (fq ^ rx) * 8];
#pragma unroll
    for (int mi = 0; mi < 4; ++mi)
      af0[mi] = *(const bf16x8*)&lb[(mi * 16 + fr) * 32 + (fq ^ rx) * 8];
    if (u + 2 < NT) {
      GLSTAGE_A(u + 2, stg);
      GLSTAGE_B(u + 2, stg, 0); GLSTAGE_B(u + 2, stg, 1);
    }
#pragma unroll
    for (int mi = 0; mi < 4; ++mi)
      af1[mi] = *(const bf16x8*)&lb[((4 + mi) * 16 + fr) * 32 + (fq ^ rx) * 8];
    if (u + 2 < NT) {
      GLSTAGE_B(u + 2, stg, 2); GLSTAGE_B(u + 2, stg, 3);
    }

    __builtin_amdgcn_s_setprio(1);
#pragma unroll
    for (int mi = 0; mi < 4; ++mi)
#pragma unroll
      for (int ni = 0; ni < 4; ++ni)
        acc[mi][ni] = __builtin_amdgcn_mfma_f32_16x16x32_bf16(
            af0[mi], bfr[ni], acc[mi][ni], 0, 0, 0);
    __builtin_amdgcn_s_setprio(0);
    __builtin_amdgcn_s_setprio(1);
#pragma unroll
    for (int mi = 0; mi < 4; ++mi)
#pragma unroll
      for (int ni = 0; ni < 4; ++ni)
        acc[4 + mi][ni] = __builtin_amdgcn_mfma_f32_16x16x32_bf16(
            af1[mi], bfr[ni], acc[4 + mi][ni], 0, 0, 0);
    __builtin_amdgcn_s_setprio(0);
    cur = (cur == 2) ? 0 : cur + 1;
  }
#undef GLSTAGE_A
#undef GLSTAGE_B

  // ---- LN epilogue: per mi-group of 16 rows ----
  __syncthreads();
  float bv4[4];
#pragma unroll
  for (int ni = 0; ni < 4; ++ni) bv4[ni] = bias[wc + ni * 16 + fr];
  float4 ga = ((const float4*)g)[lane * 2];
  float4 gb = ((const float4*)g)[lane * 2 + 1];
  float4 ba = ((const float4*)bt)[lane * 2];
  float4 bb = ((const float4*)bt)[lane * 2 + 1];
  const float gv[8] = {ga.x, ga.y, ga.z, ga.w, gb.x, gb.y, gb.z, gb.w};
  const float bv[8] = {ba.x, ba.y, ba.z, ba.w, bb.x, bb.y, bb.z, bb.w};
  float* fLN = (float*)lds;            // 16 x 512 f32, chunk-swizzled

#pragma unroll
  for (int mi = 0; mi < 8; ++mi) {
#pragma unroll
    for (int ni = 0; ni < 4; ++ni)
#pragma unroll
      for (int j = 0; j < 4; ++j) {
        const int ch = ((wid * 4 + ni) ^ (j << 2) ^ fq) & 31;   // bank-spread
        fLN[(fq * 4 + j) * 512 + ch * 16 + fr] = acc[mi][ni][j] + bv4[ni];
      }
    __syncthreads();
    // wave `wid` normalizes rows 2*wid, 2*wid+1
#pragma unroll
    for (int rr = 0; rr < 2; ++rr) {
      const int r = wid * 2 + rr;
      const int gci = lane >> 1;
      const int ch = (gci ^ ((r & 3) << 2) ^ (r >> 2)) & 31;
      const int base = r * 512 + ch * 16 + (lane & 1) * 8;
      f32x4 va = *(const f32x4*)&fLN[base];
      f32x4 vb = *(const f32x4*)&fLN[base + 4];
      float v[8] = {va[0], va[1], va[2], va[3], vb[0], vb[1], vb[2], vb[3]};
      float s = 0.f, s2 = 0.f;
#pragma unroll
      for (int e = 0; e < 8; ++e) { s += v[e]; s2 = fmaf(v[e], v[e], s2); }
#pragma unroll
      for (int off = 32; off; off >>= 1) {
        s += __shfl_xor(s, off); s2 += __shfl_xor(s2, off);
      }
      const float mu = s * (1.f / 512.f);
      const float rs = rsqrtf(s2 * (1.f / 512.f) - mu * mu + 1e-5f);
      const int rowg = m0 + mi * 16 + r;
      u16x8 rv8 = *(const u16x8*)(residb + (size_t)rowg * 512 + lane * 8);
      float rv[8];
#pragma unroll
      for (int e = 0; e < 8; ++e) rv[e] = bf2f(rv8[e]);
      float o[8];
#pragma unroll
      for (int e = 0; e < 8; ++e)
        o[e] = rv[e] + (v[e] - mu) * rs * gv[e] + bv[e];
      if (LNM == 0) {                  // window-reverse + roll(+4,+4)
        const int w = rowg >> 6, i = rowg & 63;
        const int b = w >> 6, win = w & 63;
        const int hs = (((win >> 3) << 3) + (i >> 3) + 4) & 63;
        const int ws2 = (((win & 7) << 3) + (i & 7) + 4) & 63;
        const size_t token = ((size_t)b << 12) + hs * 64 + ws2;
        u16x8 ob;
#pragma unroll
        for (int e = 0; e < 8; ++e) ob[e] = f2bf(o[e]);
        *(u16x8*)(out1b + token * 512 + lane * 8) = ob;
      } else {
        float* op = out1 + (size_t)rowg * 512 + lane * 8;
        ((f32x4*)op)[0] = (f32x4){o[0], o[1], o[2], o[3]};
        ((f32x4*)op)[1] = (f32x4){o[4], o[5], o[6], o[7]};
      }
    }
    __syncthreads();
  }
}

// ---------------------------------------------------------------------------
// Windowed cosine attention, MFMA version. One wave per (window, head).
// ---------------------------------------------------------------------------
__global__ __launch_bounds__(64)
void attn_kernel(const u16* __restrict__ qkv, const float* __restrict__ bias2,
                 const float* __restrict__ tau, u16* __restrict__ ao) {
  const int h = blockIdx.x;
  const int w = blockIdx.y;
  const int lane = threadIdx.x;
  const int fr = lane & 15, fq = lane >> 4;

  __shared__ u16 sh[7424];

  const size_t rowb = ((size_t)w * 64 + lane) * 1536 + (size_t)h * 32;
  u16x8 q8[4], k8[4], v8[4];
#pragma unroll
  for (int u = 0; u < 4; ++u) {
    q8[u] = ((const u16x8*)(qkv + rowb))[u];
    k8[u] = ((const u16x8*)(qkv + rowb + 512))[u];
    v8[u] = ((const u16x8*)(qkv + rowb + 1024))[u];
  }
  float qv[32], kv[32];
  float qn = 0.f, kn = 0.f;
#pragma unroll
  for (int d = 0; d < 32; ++d) {
    qv[d] = bf2f(q8[d >> 3][d & 7]); qn = fmaf(qv[d], qv[d], qn);
    kv[d] = bf2f(k8[d >> 3][d & 7]); kn = fmaf(kv[d], kv[d], kn);
  }
  const float itau = 1.0f / fmaxf(tau[h], 0.01f);
  const float qs = rsqrtf(fmaxf(qn, 1e-24f)) * itau;
  const float ks = rsqrtf(fmaxf(kn, 1e-24f));
#pragma unroll
  for (int u = 0; u < 4; ++u) {
    u16x8 qo, ko;
#pragma unroll
    for (int e = 0; e < 8; ++e) {
      qo[e] = f2bf(qv[u * 8 + e] * qs);
      ko[e] = f2bf(kv[u * 8 + e] * ks);
    }
    *(u16x8*)&sh[lane * 40 + u * 8] = qo;
    *(u16x8*)&sh[2560 + lane * 40 + u * 8] = ko;
  }
#pragma unroll
  for (int d = 0; d < 32; ++d)
    sh[5120 + d * 72 + lane] = v8[d >> 3][d & 7];   // V^T, raw bf16
  __syncthreads();

  f32x4 acc[4][4];
  const float4* b2 = (const float4*)bias2 + (size_t)h * 1024 + lane;
#pragma unroll
  for (int mi = 0; mi < 4; ++mi)
#pragma unroll
    for (int ni = 0; ni < 4; ++ni) {
      float4 bv = b2[(mi * 4 + ni) * 64];
      acc[mi][ni] = (f32x4){bv.x, bv.y, bv.z, bv.w};
    }
  const int win = w & 63, wh = win >> 3, ww = win & 7;
  if (wh == 7 || ww == 7) {
    int labc[4];
#pragma unroll
    for (int ni = 0; ni < 4; ++ni) {
      const int c = ni * 16 + fr;
      labc[ni] = ((wh == 7) ? (((c >> 3) < 4) ? 1 : 2) : 0) * 3
               + ((ww == 7) ? (((c & 7) < 4) ? 1 : 2) : 0);
    }
#pragma unroll
    for (int mi = 0; mi < 4; ++mi)
#pragma unroll
      for (int j = 0; j < 4; ++j) {
        const int r = mi * 16 + fq * 4 + j;
        const int lr = ((wh == 7) ? (((r >> 3) < 4) ? 1 : 2) : 0) * 3
                     + ((ww == 7) ? (((r & 7) < 4) ? 1 : 2) : 0);
#pragma unroll
        for (int ni = 0; ni < 4; ++ni)
          if (lr != labc[ni]) acc[mi][ni][j] -= 100.f;
      }
  }

  {
    bf16x8 af[4], bf[4];
#pragma unroll
    for (int mi = 0; mi < 4; ++mi)
      af[mi] = *(const bf16x8*)&sh[(mi * 16 + fr) * 40 + fq * 8];
#pragma unroll
    for (int ni = 0; ni < 4; ++ni)
      bf[ni] = *(const bf16x8*)&sh[2560 + (ni * 16 + fr) * 40 + fq * 8];
#pragma unroll
    for (int mi = 0; mi < 4; ++mi)
#pragma unroll
      for (int ni = 0; ni < 4; ++ni)
        acc[mi][ni] = __builtin_amdgcn_mfma_f32_16x16x32_bf16(
            af[mi], bf[ni], acc[mi][ni], 0, 0, 0);
  }

  float lrec[4][4];
#pragma unroll
  for (int mi = 0; mi < 4; ++mi) {
#pragma unroll
    for (int j = 0; j < 4; ++j) {
      float m4 = fmaxf(fmaxf(acc[mi][0][j], acc[mi][1][j]),
                       fmaxf(acc[mi][2][j], acc[mi][3][j]));
#pragma unroll
      for (int mk = 1; mk < 16; mk <<= 1) m4 = fmaxf(m4, __shfl_xor(m4, mk));
      float e0 = __expf(acc[mi][0][j] - m4);
      float e1 = __expf(acc[mi][1][j] - m4);
      float e2 = __expf(acc[mi][2][j] - m4);
      float e3 = __expf(acc[mi][3][j] - m4);
      float s4 = (e0 + e1) + (e2 + e3);
#pragma unroll
      for (int mk = 1; mk < 16; mk <<= 1) s4 += __shfl_xor(s4, mk);
      lrec[mi][j] = __builtin_amdgcn_rcpf(s4);
      const int r = mi * 16 + fq * 4 + j;
      sh[r * 72 +  0 + fr] = f2bf(e0);
      sh[r * 72 + 16 + fr] = f2bf(e1);
      sh[r * 72 + 32 + fr] = f2bf(e2);
      sh[r * 72 + 48 + fr] = f2bf(e3);
    }
  }
  __syncthreads();

  f32x4 acc2[4][2];
#pragma unroll
  for (int mi = 0; mi < 4; ++mi)
#pragma unroll
    for (int n2 = 0; n2 < 2; ++n2) acc2[mi][n2] = (f32x4){0.f, 0.f, 0.f, 0.f};
#pragma unroll
  for (int kk = 0; kk < 2; ++kk) {
    bf16x8 pf[4], vf[2];
#pragma unroll
    for (int mi = 0; mi < 4; ++mi)
      pf[mi] = *(const bf16x8*)&sh[(mi * 16 + fr) * 72 + kk * 32 + fq * 8];
#pragma unroll
    for (int n2 = 0; n2 < 2; ++n2)
      vf[n2] = *(const bf16x8*)&sh[5120 + (n2 * 16 + fr) * 72 + kk * 32 + fq * 8];
#pragma unroll
    for (int mi = 0; mi < 4; ++mi)
#pragma unroll
      for (int n2 = 0; n2 < 2; ++n2)
        acc2[mi][n2] = __builtin_amdgcn_mfma_f32_16x16x32_bf16(
            pf[mi], vf[n2], acc2[mi][n2], 0, 0, 0);
  }

  u16* op = ao + ((size_t)w * 64) * 512 + (size_t)h * 32;
#pragma unroll
  for (int mi = 0; mi < 4; ++mi)
#pragma unroll
    for (int j = 0; j < 4; ++j) {
      const int r = mi * 16 + fq * 4 + j;
      const float sc = lrec[mi][j];
      op[(size_t)r * 512 +  0 + fr] = f2bf(acc2[mi][0][j] * sc);
      op[(size_t)r * 512 + 16 + fr] = f2bf(acc2[mi][1][j] * sc);
    }
}

// ---------------------------------------------------------------------------
extern "C" void kernel_launch(void* const* d_in, const int* in_sizes, int n_in,
                              void* d_out, int out_size, void* d_ws, size_t ws_size,
                              hipStream_t stream) {
  const float* x      = (const float*)d_in[0];
  const float* qkv_w  = (const float*)d_in[1];
  const float* qkv_b  = (const float*)d_in[2];
  const float* proj_w = (const float*)d_in[3];
  const float* proj_b = (const float*)d_in[4];
  const float* tau    = (const float*)d_in[5];
  const float* mw1    = (const float*)d_in[6];
  const float* mb1    = (const float*)d_in[7];
  const float* mw2    = (const float*)d_in[8];
  const float* mb2    = (const float*)d_in[9];
  const float* n1g    = (const float*)d_in[10];
  const float* n1b    = (const float*)d_in[11];
  const float* n2g    = (const float*)d_in[12];
  const float* n2b    = (const float*)d_in[13];
  const float* mlp_w1 = (const float*)d_in[14];
  const float* mlp_b1 = (const float*)d_in[15];
  const float* mlp_w2 = (const float*)d_in[16];
  const float* mlp_b2 = (const float*)d_in[17];

  char* ws = (char*)d_ws;
  u16*   WQKVT  = (u16*)  (ws + 0);
  u16*   WPROJT = (u16*)  (ws + 1572864);
  u16*   WM1T   = (u16*)  (ws + 2097152);
  u16*   WM2T   = (u16*)  (ws + 4194304);
  float* BIASB  = (float*)(ws + 6291456);
  float* BIAS2  = (float*)(ws + 6553600);
  const size_t CH0 = 8388608;

  int CB = 32;
  while (CB > 1 && CH0 + (size_t)CB * 33554432ull > ws_size) CB >>= 1;
  const int NCH = 32 / CB;
  const size_t Mc = (size_t)CB * 4096;

  u16*   XW   = (u16*)  (ws + CH0);                     // Mc*1024
  u16*   QKV  = (u16*)  (ws + CH0 + Mc * 1024);         // Mc*4096 (alias HBUF)
  u16*   HBUF = QKV;
  u16*   AO   = (u16*)  (ws + CH0 + Mc * 5120);         // Mc*1024
  u16*   X1B  = (u16*)  (ws + CH0 + Mc * 7168);         // Mc*1024

  wt_kernel<<<(512 * 1536 + 255) / 256, 256, 0, stream>>>(qkv_w, WQKVT, 512, 1536);
  wt_kernel<<<(512 * 512 + 255) / 256, 256, 0, stream>>>(proj_w, WPROJT, 512, 512);
  wt_kernel<<<(512 * 2048 + 255) / 256, 256, 0, stream>>>(mlp_w1, WM1T, 512, 2048);
  wt_kernel<<<(2048 * 512 + 255) / 256, 256, 0, stream>>>(mlp_w2, WM2T, 2048, 512);
  bias_kernel<<<4096, 64, 0, stream>>>(mw1, mb1, mw2, mb2, BIASB);
  bias2_kernel<<<256, 64, 0, stream>>>(BIASB, BIAS2);

  const unsigned MB = (unsigned)(Mc / 256);    // 256-row tiles per chunk
  const unsigned LB = (unsigned)(Mc / 128);    // 128-row tiles per chunk

  for (int c = 0; c < NCH; ++c) {
    const float* xc = x + (size_t)c * Mc * 512;
    float* oc = (float*)d_out + (size_t)c * Mc * 512;

    partition_kernel<<<(unsigned)Mc, 128, 0, stream>>>(xc, XW);
    gemm8<0><<<dim3(6, MB), 512, 0, stream>>>(XW, WQKVT, qkv_b, QKV,
                                              (int)Mc, 1536, 512);
    attn_kernel<<<dim3(16, CB * 64), 64, 0, stream>>>(QKV, BIAS2, tau, AO);
    gemm_ln<0><<<LB, 512, 0, stream>>>(AO, WPROJT, proj_b, XW, n1g, n1b,
                                       nullptr, X1B, 512);
    gemm8<2><<<dim3(8, MB), 512, 0, stream>>>(X1B, WM1T, mlp_b1, HBUF,
                                              (int)Mc, 2048, 512);
    gemm_ln<1><<<LB, 512, 0, stream>>>(HBUF, WM2T, mlp_b2, X1B, n2g, n2b,
                                       oc, nullptr, 2048);
  }
}

// Round 19
// 1438.940 us; speedup vs baseline: 1.0592x; 1.0592x over previous
//
#include <hip/hip_runtime.h>

typedef unsigned short u16;
typedef __attribute__((ext_vector_type(8))) short     bf16x8;
typedef __attribute__((ext_vector_type(8))) unsigned short u16x8;
typedef __attribute__((ext_vector_type(4))) unsigned short u16x4;
typedef __attribute__((ext_vector_type(4))) float     f32x4;

#define GADDR(p) ((const __attribute__((address_space(1))) void*)(p))
#define LADDR(p) ((__attribute__((address_space(3))) void*)(p))

__device__ __forceinline__ u16 f2bf(float f) {
  unsigned u = __float_as_uint(f);
  u += 0x7fffu + ((u >> 16) & 1u);           // round-to-nearest-even
  return (u16)(u >> 16);
}
__device__ __forceinline__ float bf2f(u16 h) {
  return __uint_as_float(((unsigned)h) << 16);
}

// ---------------------------------------------------------------------------
__global__ void wt_kernel(const float* __restrict__ w, u16* __restrict__ wt,
                          int K, int N) {
  size_t idx = (size_t)blockIdx.x * 256 + threadIdx.x;
  if (idx >= (size_t)K * N) return;
  int n = (int)(idx / K);
  int k = (int)(idx % K);
  wt[idx] = f2bf(w[(size_t)k * N + n]);
}

// ---------------------------------------------------------------------------
__global__ __launch_bounds__(64)
void bias_kernel(const float* __restrict__ w1, const float* __restrict__ b1,
                 const float* __restrict__ w2, const float* __restrict__ b2,
                 float* __restrict__ out) {
  const int p = blockIdx.x;            // 0..4095  = i*64 + j
  const int i = p >> 6, j = p & 63;
  const float d0 = (float)((i >> 3) - (j >> 3));
  const float d1 = (float)((i & 7) - (j & 7));
  const float r0 = copysignf(log1pf(fabsf(d0)), d0);
  const float r1 = copysignf(log1pf(fabsf(d1)), d1);
  float part[16];
#pragma unroll
  for (int h = 0; h < 16; ++h) part[h] = 0.f;
  for (int m = threadIdx.x; m < 384; m += 64) {
    float hv = fmaxf(r0 * w1[m] + r1 * w1[384 + m] + b1[m], 0.f);
#pragma unroll
    for (int h = 0; h < 16; ++h) part[h] += hv * w2[m * 16 + h];
  }
#pragma unroll
  for (int h = 0; h < 16; ++h) {
    float v = part[h];
#pragma unroll
    for (int off = 32; off; off >>= 1) v += __shfl_xor(v, off);
    if (threadIdx.x == 0) out[(size_t)h * 4096 + p] = v + b2[h];
  }
}

// ---------------------------------------------------------------------------
__global__ __launch_bounds__(64)
void bias2_kernel(const float* __restrict__ bb, float* __restrict__ b2) {
  const int blk = blockIdx.x;          // h*16 + mi*4 + ni
  const int h = blk >> 4, mi = (blk >> 2) & 3, ni = blk & 3;
  const int lane = threadIdx.x, fr = lane & 15, fq = lane >> 4;
  float4 o;
  o.x = bb[(size_t)h * 4096 + (mi * 16 + fq * 4 + 0) * 64 + ni * 16 + fr];
  o.y = bb[(size_t)h * 4096 + (mi * 16 + fq * 4 + 1) * 64 + ni * 16 + fr];
  o.z = bb[(size_t)h * 4096 + (mi * 16 + fq * 4 + 2) * 64 + ni * 16 + fr];
  o.w = bb[(size_t)h * 4096 + (mi * 16 + fq * 4 + 3) * 64 + ni * 16 + fr];
  ((float4*)b2)[(size_t)blk * 64 + lane] = o;
}

// ---------------------------------------------------------------------------
__global__ __launch_bounds__(128)
void partition_kernel(const float* __restrict__ x, u16* __restrict__ xw) {
  const size_t r = blockIdx.x;
  const int w   = (int)(r >> 6);
  const int i   = (int)(r & 63);
  const int b   = w >> 6;
  const int win = w & 63;
  const int hs = (((win >> 3) << 3) + (i >> 3) + 4) & 63;
  const int ws2 = (((win & 7) << 3) + (i & 7) + 4) & 63;
  const float4* src = (const float4*)(x + (((size_t)b << 12) + hs * 64 + ws2) * 512);
  u16* dst = xw + r * 512;
  const int t = threadIdx.x;
  float4 v = src[t];
  u16x4 o;
  o[0] = f2bf(v.x); o[1] = f2bf(v.y); o[2] = f2bf(v.z); o[3] = f2bf(v.w);
  *(u16x4*)(dst + t * 4) = o;
}

// ---------------------------------------------------------------------------
// 256x256 tile, BK=64, 8 waves (2Mx4N), 8-phase schedule, K-loop unrolled x2
// (compile-time LDS slot). Tail waits per round-10 fix. MODE 0: bf16, 2:+GELU
// (Round-17 configuration: measured optimum. Round-18's 2-phase merge spilled
// registers -- reverted.)
// ---------------------------------------------------------------------------
template <int MODE>
__global__ __launch_bounds__(512, 1)
void gemm8(const u16* __restrict__ A, const u16* __restrict__ Wt,
           const float* __restrict__ bias, void* __restrict__ outp,
           int M, int N, int K) {
  __shared__ u16 lds[65536];           // 2 slots x 64 KiB
  const int t = threadIdx.x;           // 0..511
  const int gx = gridDim.x;            // N/256
  const int nwg = gx * gridDim.y;
  const int wg = blockIdx.y * gx + blockIdx.x;
  const int swzb = (wg & 7) * (nwg >> 3) + (wg >> 3);  // bijective: nwg%8==0
  const int n0 = (swzb % gx) * 256;
  const int m0 = (swzb / gx) * 256;

  const int lane = t & 63;
  const int wid = t >> 6;
  const int wr = (wid >> 2) * 128;
  const int wc = (wid & 3) * 64;
  const int fr = lane & 15, fq = lane >> 4;
  const int c0 = (fq ^ (fr & 7)) * 8;        // swizzled chunk slot, kk=0
  const int c1 = ((4 + fq) ^ (fr & 7)) * 8;  // kk=1

  const int tq = t >> 3;
  const int scol = ((t & 7) ^ (tq & 7)) * 8;
  const u16* Asrc = A  + (size_t)(m0 + tq) * K + scol;
  const int rowB = (tq & 31) + ((t >> 8) << 6);
  const u16* Bsrc = Wt + (size_t)(n0 + rowB) * K + scol;
  const int dA = t * 8;
  const int dB = 16384 + ((t >> 8) << 11) + t * 8;

#define SG_A(slot, src, h) do {                                               \
    const int _d = (slot) * 32768 + (h) * 4096 + dA;                          \
    const size_t _k = (size_t)(src) * 64 + (size_t)((h) * 64) * K;            \
    __builtin_amdgcn_global_load_lds(GADDR(Asrc + _k), LADDR(&lds[_d]), 16, 0, 0); \
    __builtin_amdgcn_global_load_lds(GADDR(Asrc + _k + (size_t)128 * K),      \
                                     LADDR(&lds[_d + 8192]), 16, 0, 0);       \
  } while (0)
#define SG_B(slot, src, h) do {                                               \
    const int _d = (slot) * 32768 + (h) * 2048 + dB;                          \
    const size_t _k = (size_t)(src) * 64 + (size_t)((h) * 32) * K;            \
    __builtin_amdgcn_global_load_lds(GADDR(Bsrc + _k), LADDR(&lds[_d]), 16, 0, 0); \
    __builtin_amdgcn_global_load_lds(GADDR(Bsrc + _k + (size_t)128 * K),      \
                                     LADDR(&lds[_d + 8192]), 16, 0, 0);       \
  } while (0)

  f32x4 acc[8][4];
#pragma unroll
  for (int a = 0; a < 8; ++a)
#pragma unroll
    for (int b = 0; b < 4; ++b) acc[a][b] = (f32x4){0.f, 0.f, 0.f, 0.f};

  const int NT = K >> 6;               // BK=64 tiles; NT is even (8 or 32)
  SG_A(0, 0, 0); SG_A(0, 0, 1); SG_B(0, 0, 0); SG_B(0, 0, 1);
  SG_A(1, 1, 0); SG_B(1, 1, 0); SG_B(1, 1, 1);
  asm volatile("s_waitcnt vmcnt(6)" ::: "memory");
  __builtin_amdgcn_s_barrier();

#define TILE_BODY(S, SLOT, NSLOT, P0_COND)                                    \
  {                                                                           \
    const u16* la = lds + (SLOT) * 32768;                                     \
    const u16* lb = la + 16384;                                               \
    bf16x8 af[8], bf0[4], bf1[4];                                             \
    _Pragma("unroll")                                                         \
    for (int mi = 0; mi < 4; ++mi) {                                          \
      const int r = (wr + mi * 16 + fr) * 64;                                 \
      af[mi * 2]     = *(const bf16x8*)&la[r + c0];                           \
      af[mi * 2 + 1] = *(const bf16x8*)&la[r + c1];                           \
    }                                                                         \
    _Pragma("unroll")                                                         \
    for (int ni = 0; ni < 2; ++ni) {                                          \
      const int r = (wc + ni * 16 + fr) * 64;                                 \
      bf0[ni * 2]     = *(const bf16x8*)&lb[r + c0];                          \
      bf0[ni * 2 + 1] = *(const bf16x8*)&lb[r + c1];                          \
    }                                                                         \
    if (P0_COND) SG_A(NSLOT, (S) + 1, 1);                                     \
    __builtin_amdgcn_s_barrier();                                             \
    asm volatile("s_waitcnt lgkmcnt(0)" ::: "memory");                        \
    __builtin_amdgcn_sched_barrier(0);                                        \
    __builtin_amdgcn_s_setprio(1);                                            \
    _Pragma("unroll")                                                         \
    for (int mi = 0; mi < 4; ++mi)                                            \
      _Pragma("unroll")                                                       \
      for (int ni = 0; ni < 2; ++ni) {                                        \
        acc[mi][ni] = __builtin_amdgcn_mfma_f32_16x16x32_bf16(                \
            af[mi * 2], bf0[ni * 2], acc[mi][ni], 0, 0, 0);                   \
        acc[mi][ni] = __builtin_amdgcn_mfma_f32_16x16x32_bf16(                \
            af[mi * 2 + 1], bf0[ni * 2 + 1], acc[mi][ni], 0, 0, 0);           \
      }                                                                       \
    __builtin_amdgcn_s_setprio(0);                                            \
    __builtin_amdgcn_s_barrier();                                             \
    _Pragma("unroll")                                                         \
    for (int ni = 0; ni < 2; ++ni) {                                          \
      const int r = (wc + 32 + ni * 16 + fr) * 64;                            \
      bf1[ni * 2]     = *(const bf16x8*)&lb[r + c0];                          \
      bf1[ni * 2 + 1] = *(const bf16x8*)&lb[r + c1];                          \
    }                                                                         \
    if ((S) + 2 < NT) SG_A(SLOT, (S) + 2, 0);                                 \
    __builtin_amdgcn_s_barrier();                                             \
    asm volatile("s_waitcnt lgkmcnt(0)" ::: "memory");                        \
    __builtin_amdgcn_sched_barrier(0);                                        \
    __builtin_amdgcn_s_setprio(1);                                            \
    _Pragma("unroll")                                                         \
    for (int mi = 0; mi < 4; ++mi)                                            \
      _Pragma("unroll")                                                       \
      for (int ni = 0; ni < 2; ++ni) {                                        \
        acc[mi][2 + ni] = __builtin_amdgcn_mfma_f32_16x16x32_bf16(            \
            af[mi * 2], bf1[ni * 2], acc[mi][2 + ni], 0, 0, 0);               \
        acc[mi][2 + ni] = __builtin_amdgcn_mfma_f32_16x16x32_bf16(            \
            af[mi * 2 + 1], bf1[ni * 2 + 1], acc[mi][2 + ni], 0, 0, 0);       \
      }                                                                       \
    __builtin_amdgcn_s_setprio(0);                                            \
    __builtin_amdgcn_s_barrier();                                             \
    _Pragma("unroll")                                                         \
    for (int mi = 0; mi < 4; ++mi) {                                          \
      const int r = (wr + 64 + mi * 16 + fr) * 64;                            \
      af[mi * 2]     = *(const bf16x8*)&la[r + c0];                           \
      af[mi * 2 + 1] = *(const bf16x8*)&la[r + c1];                           \
    }                                                                         \
    if ((S) + 2 < NT) SG_B(SLOT, (S) + 2, 0);                                 \
    __builtin_amdgcn_s_barrier();                                             \
    asm volatile("s_waitcnt lgkmcnt(0)" ::: "memory");                        \
    __builtin_amdgcn_sched_barrier(0);                                        \
    __builtin_amdgcn_s_setprio(1);                                            \
    _Pragma("unroll")                                                         \
    for (int mi = 0; mi < 4; ++mi)                                            \
      _Pragma("unroll")                                                       \
      for (int ni = 0; ni < 2; ++ni) {                                        \
        acc[4 + mi][ni] = __builtin_amdgcn_mfma_f32_16x16x32_bf16(            \
            af[mi * 2], bf0[ni * 2], acc[4 + mi][ni], 0, 0, 0);               \
        acc[4 + mi][ni] = __builtin_amdgcn_mfma_f32_16x16x32_bf16(            \
            af[mi * 2 + 1], bf0[ni * 2 + 1], acc[4 + mi][ni], 0, 0, 0);       \
      }                                                                       \
    __builtin_amdgcn_s_setprio(0);                                            \
    __builtin_amdgcn_s_barrier();                                             \
    if ((S) + 2 < NT) SG_B(SLOT, (S) + 2, 1);                                 \
    __builtin_amdgcn_s_barrier();                                             \
    __builtin_amdgcn_s_setprio(1);                                            \
    _Pragma("unroll")                                                         \
    for (int mi = 0; mi < 4; ++mi)                                            \
      _Pragma("unroll")                                                       \
      for (int ni = 0; ni < 2; ++ni) {                                        \
        acc[4 + mi][2 + ni] = __builtin_amdgcn_mfma_f32_16x16x32_bf16(        \
            af[mi * 2], bf1[ni * 2], acc[4 + mi][2 + ni], 0, 0, 0);           \
        acc[4 + mi][2 + ni] = __builtin_amdgcn_mfma_f32_16x16x32_bf16(        \
            af[mi * 2 + 1], bf1[ni * 2 + 1], acc[4 + mi][2 + ni], 0, 0, 0);   \
      }                                                                       \
    __builtin_amdgcn_s_setprio(0);                                            \
    if ((S) + 2 < NT) asm volatile("s_waitcnt vmcnt(6)" ::: "memory");        \
    else              asm volatile("s_waitcnt vmcnt(0)" ::: "memory");        \
    __builtin_amdgcn_s_barrier();                                             \
  }

  for (int s = 0; s < NT; s += 2) {
    TILE_BODY(s,     0, 1, true);
    TILE_BODY(s + 1, 1, 0, (s + 2 < NT));
  }
#undef TILE_BODY
#undef SG_A
#undef SG_B
  asm volatile("s_waitcnt vmcnt(0)" ::: "memory");  // drain before LDS reuse
  __syncthreads();

  // ---- epilogue: swizzled LDS stage -> coalesced stores ----
  float bv4[4];
#pragma unroll
  for (int ni = 0; ni < 4; ++ni) bv4[ni] = bias[n0 + wc + ni * 16 + fr];

  u16* uW = &lds[wid * 8192];
  u16* og = (u16*)outp;
#pragma unroll
  for (int mi = 0; mi < 8; ++mi) {
#pragma unroll
    for (int ni = 0; ni < 4; ++ni)
#pragma unroll
      for (int j = 0; j < 4; ++j) {
        float v = acc[mi][ni][j] + bv4[ni];
        if (MODE == 2) {               // tanh-approx GELU
          const float a2 = v * (1.5957691216f + 0.0713548162f * v * v);
          const float e = __expf(a2);
          v = v * (e * __builtin_amdgcn_rcpf(e + 1.0f));
        }
        uW[(fq * 4 + j) * 64 + ((ni ^ j ^ fq) & 3) * 16 + fr] = f2bf(v);
      }
#pragma unroll
    for (int p = 0; p < 2; ++p) {
      const int r = p * 8 + (lane >> 3);
      const int sg = (((lane & 7) >> 1) ^ (r & 3) ^ ((r >> 2) & 3)) & 3;
      u16x8 v8 = *(const u16x8*)&uW[r * 64 + sg * 16 + (lane & 1) * 8];
      const int row = m0 + wr + mi * 16 + r;
      *(u16x8*)&og[(size_t)row * N + n0 + wc + (lane & 7) * 8] = v8;
    }
  }
}

// ---------------------------------------------------------------------------
// Fused GEMM(128x512 tile) + residual + LayerNorm, bf16-residual edition.
// LNM 0: A=AO, resid=XW (window layout, row=rowg); writes X1B (token layout).
// LNM 1: A=HBUF, resid=X1B (row=rowg); writes d_out (f32).
// ---------------------------------------------------------------------------
template <int LNM>
__global__ __launch_bounds__(512, 1)
void gemm_ln(const u16* __restrict__ A, const u16* __restrict__ Wt,
             const float* __restrict__ bias, const u16* __restrict__ residb,
             const float* __restrict__ g, const float* __restrict__ bt,
             float* __restrict__ out1, u16* __restrict__ out1b, int K) {
  __shared__ u16 lds[61440];
  const int t = threadIdx.x;
  const int nwg = gridDim.x;
  const int wg = blockIdx.x;
  const int swz = (wg & 7) * (nwg >> 3) + (wg >> 3);   // nwg % 8 == 0
  const int m0 = swz * 128;

  const int lane = t & 63;
  const int wid = t >> 6;
  const int wc = wid * 64;
  const int fr = lane & 15, fq = lane >> 4;
  const int rx = (fr >> 1) & 3;

  const int srow = t >> 2;             // 0..127
  const int schk = ((t & 3) ^ ((srow >> 1) & 3)) * 8;
  const u16* Ag = A  + (size_t)(m0 + srow) * K + schk;
  const u16* Bg = Wt + (size_t)srow * K + schk;

#define GLSTAGE_A(tile, buf)                                                  \
    __builtin_amdgcn_global_load_lds(GADDR(Ag + (size_t)(tile) * 32),         \
        LADDR(&lds[(buf) * 20480 + t * 8]), 16, 0, 0)
#define GLSTAGE_B(tile, buf, p)                                               \
    __builtin_amdgcn_global_load_lds(                                         \
        GADDR(Bg + (size_t)(p) * 128 * K + (size_t)(tile) * 32),              \
        LADDR(&lds[(buf) * 20480 + 4096 + (p) * 4096 + t * 8]), 16, 0, 0)

  f32x4 acc[8][4];
#pragma unroll
  for (int a = 0; a < 8; ++a)
#pragma unroll
    for (int b = 0; b < 4; ++b) acc[a][b] = (f32x4){0.f, 0.f, 0.f, 0.f};

  const int NT = K >> 5;
  GLSTAGE_A(0, 0);
  GLSTAGE_B(0, 0, 0); GLSTAGE_B(0, 0, 1); GLSTAGE_B(0, 0, 2); GLSTAGE_B(0, 0, 3);
  GLSTAGE_A(1, 1);
  GLSTAGE_B(1, 1, 0); GLSTAGE_B(1, 1, 1); GLSTAGE_B(1, 1, 2); GLSTAGE_B(1, 1, 3);

  int cur = 0;
  for (int u = 0; u < NT; ++u) {
    if (u + 1 < NT) asm volatile("s_waitcnt vmcnt(5)" ::: "memory");
    else            asm volatile("s_waitcnt vmcnt(0)" ::: "memory");
    __builtin_amdgcn_s_barrier();

    const u16* lb = lds + cur * 20480;
    const int stg = (cur == 0) ? 2 : cur - 1;   // (cur+2)%3
    bf16x8 bfr[4], af0[4], af1[4];
#pragma unroll
    for (int ni = 0; ni < 4; ++ni)
      bfr[ni] = *(const bf16x8*)&lb[4096 + (wc + ni * 16 + fr) * 32 + (fq ^ rx) * 8];
#pragma unroll
    for (int mi = 0; mi < 4; ++mi)
      af0[mi] = *(const bf16x8*)&lb[(mi * 16 + fr) * 32 + (fq ^ rx) * 8];
    if (u + 2 < NT) {
      GLSTAGE_A(u + 2, stg);
      GLSTAGE_B(u + 2, stg, 0); GLSTAGE_B(u + 2, stg, 1);
    }
#pragma unroll
    for (int mi = 0; mi < 4; ++mi)
      af1[mi] = *(const bf16x8*)&lb[((4 + mi) * 16 + fr) * 32 + (fq ^ rx) * 8];
    if (u + 2 < NT) {
      GLSTAGE_B(u + 2, stg, 2); GLSTAGE_B(u + 2, stg, 3);
    }

    __builtin_amdgcn_s_setprio(1);
#pragma unroll
    for (int mi = 0; mi < 4; ++mi)
#pragma unroll
      for (int ni = 0; ni < 4; ++ni)
        acc[mi][ni] = __builtin_amdgcn_mfma_f32_16x16x32_bf16(
            af0[mi], bfr[ni], acc[mi][ni], 0, 0, 0);
    __builtin_amdgcn_s_setprio(0);
    __builtin_amdgcn_s_setprio(1);
#pragma unroll
    for (int mi = 0; mi < 4; ++mi)
#pragma unroll
      for (int ni = 0; ni < 4; ++ni)
        acc[4 + mi][ni] = __builtin_amdgcn_mfma_f32_16x16x32_bf16(
            af1[mi], bfr[ni], acc[4 + mi][ni], 0, 0, 0);
    __builtin_amdgcn_s_setprio(0);
    cur = (cur == 2) ? 0 : cur + 1;
  }
#undef GLSTAGE_A
#undef GLSTAGE_B

  // ---- LN epilogue: per mi-group of 16 rows ----
  __syncthreads();
  float bv4[4];
#pragma unroll
  for (int ni = 0; ni < 4; ++ni) bv4[ni] = bias[wc + ni * 16 + fr];
  float4 ga = ((const float4*)g)[lane * 2];
  float4 gb = ((const float4*)g)[lane * 2 + 1];
  float4 ba = ((const float4*)bt)[lane * 2];
  float4 bb = ((const float4*)bt)[lane * 2 + 1];
  const float gv[8] = {ga.x, ga.y, ga.z, ga.w, gb.x, gb.y, gb.z, gb.w};
  const float bv[8] = {ba.x, ba.y, ba.z, ba.w, bb.x, bb.y, bb.z, bb.w};
  float* fLN = (float*)lds;            // 16 x 512 f32, chunk-swizzled

#pragma unroll
  for (int mi = 0; mi < 8; ++mi) {
#pragma unroll
    for (int ni = 0; ni < 4; ++ni)
#pragma unroll
      for (int j = 0; j < 4; ++j) {
        const int ch = ((wid * 4 + ni) ^ (j << 2) ^ fq) & 31;   // bank-spread
        fLN[(fq * 4 + j) * 512 + ch * 16 + fr] = acc[mi][ni][j] + bv4[ni];
      }
    __syncthreads();
    // wave `wid` normalizes rows 2*wid, 2*wid+1
#pragma unroll
    for (int rr = 0; rr < 2; ++rr) {
      const int r = wid * 2 + rr;
      const int gci = lane >> 1;
      const int ch = (gci ^ ((r & 3) << 2) ^ (r >> 2)) & 31;
      const int base = r * 512 + ch * 16 + (lane & 1) * 8;
      f32x4 va = *(const f32x4*)&fLN[base];
      f32x4 vb = *(const f32x4*)&fLN[base + 4];
      float v[8] = {va[0], va[1], va[2], va[3], vb[0], vb[1], vb[2], vb[3]};
      float s = 0.f, s2 = 0.f;
#pragma unroll
      for (int e = 0; e < 8; ++e) { s += v[e]; s2 = fmaf(v[e], v[e], s2); }
#pragma unroll
      for (int off = 32; off; off >>= 1) {
        s += __shfl_xor(s, off); s2 += __shfl_xor(s2, off);
      }
      const float mu = s * (1.f / 512.f);
      const float rs = rsqrtf(s2 * (1.f / 512.f) - mu * mu + 1e-5f);
      const int rowg = m0 + mi * 16 + r;
      u16x8 rv8 = *(const u16x8*)(residb + (size_t)rowg * 512 + lane * 8);
      float rv[8];
#pragma unroll
      for (int e = 0; e < 8; ++e) rv[e] = bf2f(rv8[e]);
      float o[8];
#pragma unroll
      for (int e = 0; e < 8; ++e)
        o[e] = rv[e] + (v[e] - mu) * rs * gv[e] + bv[e];
      if (LNM == 0) {                  // window-reverse + roll(+4,+4)
        const int w = rowg >> 6, i = rowg & 63;
        const int b = w >> 6, win = w & 63;
        const int hs = (((win >> 3) << 3) + (i >> 3) + 4) & 63;
        const int ws2 = (((win & 7) << 3) + (i & 7) + 4) & 63;
        const size_t token = ((size_t)b << 12) + hs * 64 + ws2;
        u16x8 ob;
#pragma unroll
        for (int e = 0; e < 8; ++e) ob[e] = f2bf(o[e]);
        *(u16x8*)(out1b + token * 512 + lane * 8) = ob;
      } else {
        float* op = out1 + (size_t)rowg * 512 + lane * 8;
        ((f32x4*)op)[0] = (f32x4){o[0], o[1], o[2], o[3]};
        ((f32x4*)op)[1] = (f32x4){o[4], o[5], o[6], o[7]};
      }
    }
    __syncthreads();
  }
}

// ---------------------------------------------------------------------------
// Windowed cosine attention, MFMA version. One wave per (window, head).
// ---------------------------------------------------------------------------
__global__ __launch_bounds__(64)
void attn_kernel(const u16* __restrict__ qkv, const float* __restrict__ bias2,
                 const float* __restrict__ tau, u16* __restrict__ ao) {
  const int h = blockIdx.x;
  const int w = blockIdx.y;
  const int lane = threadIdx.x;
  const int fr = lane & 15, fq = lane >> 4;

  __shared__ u16 sh[7424];

  const size_t rowb = ((size_t)w * 64 + lane) * 1536 + (size_t)h * 32;
  u16x8 q8[4], k8[4], v8[4];
#pragma unroll
  for (int u = 0; u < 4; ++u) {
    q8[u] = ((const u16x8*)(qkv + rowb))[u];
    k8[u] = ((const u16x8*)(qkv + rowb + 512))[u];
    v8[u] = ((const u16x8*)(qkv + rowb + 1024))[u];
  }
  float qv[32], kv[32];
  float qn = 0.f, kn = 0.f;
#pragma unroll
  for (int d = 0; d < 32; ++d) {
    qv[d] = bf2f(q8[d >> 3][d & 7]); qn = fmaf(qv[d], qv[d], qn);
    kv[d] = bf2f(k8[d >> 3][d & 7]); kn = fmaf(kv[d], kv[d], kn);
  }
  const float itau = 1.0f / fmaxf(tau[h], 0.01f);
  const float qs = rsqrtf(fmaxf(qn, 1e-24f)) * itau;
  const float ks = rsqrtf(fmaxf(kn, 1e-24f));
#pragma unroll
  for (int u = 0; u < 4; ++u) {
    u16x8 qo, ko;
#pragma unroll
    for (int e = 0; e < 8; ++e) {
      qo[e] = f2bf(qv[u * 8 + e] * qs);
      ko[e] = f2bf(kv[u * 8 + e] * ks);
    }
    *(u16x8*)&sh[lane * 40 + u * 8] = qo;
    *(u16x8*)&sh[2560 + lane * 40 + u * 8] = ko;
  }
#pragma unroll
  for (int d = 0; d < 32; ++d)
    sh[5120 + d * 72 + lane] = v8[d >> 3][d & 7];   // V^T, raw bf16
  __syncthreads();

  f32x4 acc[4][4];
  const float4* b2 = (const float4*)bias2 + (size_t)h * 1024 + lane;
#pragma unroll
  for (int mi = 0; mi < 4; ++mi)
#pragma unroll
    for (int ni = 0; ni < 4; ++ni) {
      float4 bv = b2[(mi * 4 + ni) * 64];
      acc[mi][ni] = (f32x4){bv.x, bv.y, bv.z, bv.w};
    }
  const int win = w & 63, wh = win >> 3, ww = win & 7;
  if (wh == 7 || ww == 7) {
    int labc[4];
#pragma unroll
    for (int ni = 0; ni < 4; ++ni) {
      const int c = ni * 16 + fr;
      labc[ni] = ((wh == 7) ? (((c >> 3) < 4) ? 1 : 2) : 0) * 3
               + ((ww == 7) ? (((c & 7) < 4) ? 1 : 2) : 0);
    }
#pragma unroll
    for (int mi = 0; mi < 4; ++mi)
#pragma unroll
      for (int j = 0; j < 4; ++j) {
        const int r = mi * 16 + fq * 4 + j;
        const int lr = ((wh == 7) ? (((r >> 3) < 4) ? 1 : 2) : 0) * 3
                     + ((ww == 7) ? (((r & 7) < 4) ? 1 : 2) : 0);
#pragma unroll
        for (int ni = 0; ni < 4; ++ni)
          if (lr != labc[ni]) acc[mi][ni][j] -= 100.f;
      }
  }

  {
    bf16x8 af[4], bf[4];
#pragma unroll
    for (int mi = 0; mi < 4; ++mi)
      af[mi] = *(const bf16x8*)&sh[(mi * 16 + fr) * 40 + fq * 8];
#pragma unroll
    for (int ni = 0; ni < 4; ++ni)
      bf[ni] = *(const bf16x8*)&sh[2560 + (ni * 16 + fr) * 40 + fq * 8];
#pragma unroll
    for (int mi = 0; mi < 4; ++mi)
#pragma unroll
      for (int ni = 0; ni < 4; ++ni)
        acc[mi][ni] = __builtin_amdgcn_mfma_f32_16x16x32_bf16(
            af[mi], bf[ni], acc[mi][ni], 0, 0, 0);
  }

  float lrec[4][4];
#pragma unroll
  for (int mi = 0; mi < 4; ++mi) {
#pragma unroll
    for (int j = 0; j < 4; ++j) {
      float m4 = fmaxf(fmaxf(acc[mi][0][j], acc[mi][1][j]),
                       fmaxf(acc[mi][2][j], acc[mi][3][j]));
#pragma unroll
      for (int mk = 1; mk < 16; mk <<= 1) m4 = fmaxf(m4, __shfl_xor(m4, mk));
      float e0 = __expf(acc[mi][0][j] - m4);
      float e1 = __expf(acc[mi][1][j] - m4);
      float e2 = __expf(acc[mi][2][j] - m4);
      float e3 = __expf(acc[mi][3][j] - m4);
      float s4 = (e0 + e1) + (e2 + e3);
#pragma unroll
      for (int mk = 1; mk < 16; mk <<= 1) s4 += __shfl_xor(s4, mk);
      lrec[mi][j] = __builtin_amdgcn_rcpf(s4);
      const int r = mi * 16 + fq * 4 + j;
      sh[r * 72 +  0 + fr] = f2bf(e0);
      sh[r * 72 + 16 + fr] = f2bf(e1);
      sh[r * 72 + 32 + fr] = f2bf(e2);
      sh[r * 72 + 48 + fr] = f2bf(e3);
    }
  }
  __syncthreads();

  f32x4 acc2[4][2];
#pragma unroll
  for (int mi = 0; mi < 4; ++mi)
#pragma unroll
    for (int n2 = 0; n2 < 2; ++n2) acc2[mi][n2] = (f32x4){0.f, 0.f, 0.f, 0.f};
#pragma unroll
  for (int kk = 0; kk < 2; ++kk) {
    bf16x8 pf[4], vf[2];
#pragma unroll
    for (int mi = 0; mi < 4; ++mi)
      pf[mi] = *(const bf16x8*)&sh[(mi * 16 + fr) * 72 + kk * 32 + fq * 8];
#pragma unroll
    for (int n2 = 0; n2 < 2; ++n2)
      vf[n2] = *(const bf16x8*)&sh[5120 + (n2 * 16 + fr) * 72 + kk * 32 + fq * 8];
#pragma unroll
    for (int mi = 0; mi < 4; ++mi)
#pragma unroll
      for (int n2 = 0; n2 < 2; ++n2)
        acc2[mi][n2] = __builtin_amdgcn_mfma_f32_16x16x32_bf16(
            pf[mi], vf[n2], acc2[mi][n2], 0, 0, 0);
  }

  u16* op = ao + ((size_t)w * 64) * 512 + (size_t)h * 32;
#pragma unroll
  for (int mi = 0; mi < 4; ++mi)
#pragma unroll
    for (int j = 0; j < 4; ++j) {
      const int r = mi * 16 + fq * 4 + j;
      const float sc = lrec[mi][j];
      op[(size_t)r * 512 +  0 + fr] = f2bf(acc2[mi][0][j] * sc);
      op[(size_t)r * 512 + 16 + fr] = f2bf(acc2[mi][1][j] * sc);
    }
}

// ---------------------------------------------------------------------------
extern "C" void kernel_launch(void* const* d_in, const int* in_sizes, int n_in,
                              void* d_out, int out_size, void* d_ws, size_t ws_size,
                              hipStream_t stream) {
  const float* x      = (const float*)d_in[0];
  const float* qkv_w  = (const float*)d_in[1];
  const float* qkv_b  = (const float*)d_in[2];
  const float* proj_w = (const float*)d_in[3];
  const float* proj_b = (const float*)d_in[4];
  const float* tau    = (const float*)d_in[5];
  const float* mw1    = (const float*)d_in[6];
  const float* mb1    = (const float*)d_in[7];
  const float* mw2    = (const float*)d_in[8];
  const float* mb2    = (const float*)d_in[9];
  const float* n1g    = (const float*)d_in[10];
  const float* n1b    = (const float*)d_in[11];
  const float* n2g    = (const float*)d_in[12];
  const float* n2b    = (const float*)d_in[13];
  const float* mlp_w1 = (const float*)d_in[14];
  const float* mlp_b1 = (const float*)d_in[15];
  const float* mlp_w2 = (const float*)d_in[16];
  const float* mlp_b2 = (const float*)d_in[17];

  char* ws = (char*)d_ws;
  u16*   WQKVT  = (u16*)  (ws + 0);
  u16*   WPROJT = (u16*)  (ws + 1572864);
  u16*   WM1T   = (u16*)  (ws + 2097152);
  u16*   WM2T   = (u16*)  (ws + 4194304);
  float* BIASB  = (float*)(ws + 6291456);
  float* BIAS2  = (float*)(ws + 6553600);
  const size_t CH0 = 8388608;

  int CB = 32;
  while (CB > 1 && CH0 + (size_t)CB * 33554432ull > ws_size) CB >>= 1;
  const int NCH = 32 / CB;
  const size_t Mc = (size_t)CB * 4096;

  u16*   XW   = (u16*)  (ws + CH0);                     // Mc*1024
  u16*   QKV  = (u16*)  (ws + CH0 + Mc * 1024);         // Mc*4096 (alias HBUF)
  u16*   HBUF = QKV;
  u16*   AO   = (u16*)  (ws + CH0 + Mc * 5120);         // Mc*1024
  u16*   X1B  = (u16*)  (ws + CH0 + Mc * 7168);         // Mc*1024

  wt_kernel<<<(512 * 1536 + 255) / 256, 256, 0, stream>>>(qkv_w, WQKVT, 512, 1536);
  wt_kernel<<<(512 * 512 + 255) / 256, 256, 0, stream>>>(proj_w, WPROJT, 512, 512);
  wt_kernel<<<(512 * 2048 + 255) / 256, 256, 0, stream>>>(mlp_w1, WM1T, 512, 2048);
  wt_kernel<<<(2048 * 512 + 255) / 256, 256, 0, stream>>>(mlp_w2, WM2T, 2048, 512);
  bias_kernel<<<4096, 64, 0, stream>>>(mw1, mb1, mw2, mb2, BIASB);
  bias2_kernel<<<256, 64, 0, stream>>>(BIASB, BIAS2);

  const unsigned MB = (unsigned)(Mc / 256);    // 256-row tiles per chunk
  const unsigned LB = (unsigned)(Mc / 128);    // 128-row tiles per chunk

  for (int c = 0; c < NCH; ++c) {
    const float* xc = x + (size_t)c * Mc * 512;
    float* oc = (float*)d_out + (size_t)c * Mc * 512;

    partition_kernel<<<(unsigned)Mc, 128, 0, stream>>>(xc, XW);
    gemm8<0><<<dim3(6, MB), 512, 0, stream>>>(XW, WQKVT, qkv_b, QKV,
                                              (int)Mc, 1536, 512);
    attn_kernel<<<dim3(16, CB * 64), 64, 0, stream>>>(QKV, BIAS2, tau, AO);
    gemm_ln<0><<<LB, 512, 0, stream>>>(AO, WPROJT, proj_b, XW, n1g, n1b,
                                       nullptr, X1B, 512);
    gemm8<2><<<dim3(8, MB), 512, 0, stream>>>(X1B, WM1T, mlp_b1, HBUF,
                                              (int)Mc, 2048, 512);
    gemm_ln<1><<<LB, 512, 0, stream>>>(HBUF, WM2T, mlp_b2, X1B, n2g, n2b,
                                       oc, nullptr, 2048);
  }
}

// Round 20
// 1423.657 us; speedup vs baseline: 1.0706x; 1.0107x over previous
//
#include <hip/hip_runtime.h>

typedef unsigned short u16;
typedef __attribute__((ext_vector_type(8))) short     bf16x8;
typedef __attribute__((ext_vector_type(8))) unsigned short u16x8;
typedef __attribute__((ext_vector_type(4))) unsigned short u16x4;
typedef __attribute__((ext_vector_type(4))) float     f32x4;

#define GADDR(p) ((const __attribute__((address_space(1))) void*)(p))
#define LADDR(p) ((__attribute__((address_space(3))) void*)(p))

__device__ __forceinline__ u16 f2bf(float f) {
  unsigned u = __float_as_uint(f);
  u += 0x7fffu + ((u >> 16) & 1u);           // round-to-nearest-even
  return (u16)(u >> 16);
}
__device__ __forceinline__ float bf2f(u16 h) {
  return __uint_as_float(((unsigned)h) << 16);
}

// ---------------------------------------------------------------------------
__global__ void wt_kernel(const float* __restrict__ w, u16* __restrict__ wt,
                          int K, int N) {
  size_t idx = (size_t)blockIdx.x * 256 + threadIdx.x;
  if (idx >= (size_t)K * N) return;
  int n = (int)(idx / K);
  int k = (int)(idx % K);
  wt[idx] = f2bf(w[(size_t)k * N + n]);
}

// ---------------------------------------------------------------------------
__global__ __launch_bounds__(64)
void bias_kernel(const float* __restrict__ w1, const float* __restrict__ b1,
                 const float* __restrict__ w2, const float* __restrict__ b2,
                 float* __restrict__ out) {
  const int p = blockIdx.x;            // 0..4095  = i*64 + j
  const int i = p >> 6, j = p & 63;
  const float d0 = (float)((i >> 3) - (j >> 3));
  const float d1 = (float)((i & 7) - (j & 7));
  const float r0 = copysignf(log1pf(fabsf(d0)), d0);
  const float r1 = copysignf(log1pf(fabsf(d1)), d1);
  float part[16];
#pragma unroll
  for (int h = 0; h < 16; ++h) part[h] = 0.f;
  for (int m = threadIdx.x; m < 384; m += 64) {
    float hv = fmaxf(r0 * w1[m] + r1 * w1[384 + m] + b1[m], 0.f);
#pragma unroll
    for (int h = 0; h < 16; ++h) part[h] += hv * w2[m * 16 + h];
  }
#pragma unroll
  for (int h = 0; h < 16; ++h) {
    float v = part[h];
#pragma unroll
    for (int off = 32; off; off >>= 1) v += __shfl_xor(v, off);
    if (threadIdx.x == 0) out[(size_t)h * 4096 + p] = v + b2[h];
  }
}

// ---------------------------------------------------------------------------
__global__ __launch_bounds__(64)
void bias2_kernel(const float* __restrict__ bb, float* __restrict__ b2) {
  const int blk = blockIdx.x;          // h*16 + mi*4 + ni
  const int h = blk >> 4, mi = (blk >> 2) & 3, ni = blk & 3;
  const int lane = threadIdx.x, fr = lane & 15, fq = lane >> 4;
  float4 o;
  o.x = bb[(size_t)h * 4096 + (mi * 16 + fq * 4 + 0) * 64 + ni * 16 + fr];
  o.y = bb[(size_t)h * 4096 + (mi * 16 + fq * 4 + 1) * 64 + ni * 16 + fr];
  o.z = bb[(size_t)h * 4096 + (mi * 16 + fq * 4 + 2) * 64 + ni * 16 + fr];
  o.w = bb[(size_t)h * 4096 + (mi * 16 + fq * 4 + 3) * 64 + ni * 16 + fr];
  ((float4*)b2)[(size_t)blk * 64 + lane] = o;
}

// ---------------------------------------------------------------------------
__global__ __launch_bounds__(128)
void partition_kernel(const float* __restrict__ x, u16* __restrict__ xw) {
  const size_t r = blockIdx.x;
  const int w   = (int)(r >> 6);
  const int i   = (int)(r & 63);
  const int b   = w >> 6;
  const int win = w & 63;
  const int hs = (((win >> 3) << 3) + (i >> 3) + 4) & 63;
  const int ws2 = (((win & 7) << 3) + (i & 7) + 4) & 63;
  const float4* src = (const float4*)(x + (((size_t)b << 12) + hs * 64 + ws2) * 512);
  u16* dst = xw + r * 512;
  const int t = threadIdx.x;
  float4 v = src[t];
  u16x4 o;
  o[0] = f2bf(v.x); o[1] = f2bf(v.y); o[2] = f2bf(v.z); o[3] = f2bf(v.w);
  *(u16x4*)(dst + t * 4) = o;
}

// ---------------------------------------------------------------------------
// 256x256 tile, BK=64, 8 waves (2Mx4N), 8-phase schedule, K-loop unrolled x2
// (compile-time LDS slot). Tail waits per round-10 fix. MODE 0: bf16, 2:+GELU
// (Round-17 configuration: measured optimum.)
// ---------------------------------------------------------------------------
template <int MODE>
__global__ __launch_bounds__(512, 1)
void gemm8(const u16* __restrict__ A, const u16* __restrict__ Wt,
           const float* __restrict__ bias, void* __restrict__ outp,
           int M, int N, int K) {
  __shared__ u16 lds[65536];           // 2 slots x 64 KiB
  const int t = threadIdx.x;           // 0..511
  const int gx = gridDim.x;            // N/256
  const int nwg = gx * gridDim.y;
  const int wg = blockIdx.y * gx + blockIdx.x;
  const int swzb = (wg & 7) * (nwg >> 3) + (wg >> 3);  // bijective: nwg%8==0
  const int n0 = (swzb % gx) * 256;
  const int m0 = (swzb / gx) * 256;

  const int lane = t & 63;
  const int wid = t >> 6;
  const int wr = (wid >> 2) * 128;
  const int wc = (wid & 3) * 64;
  const int fr = lane & 15, fq = lane >> 4;
  const int c0 = (fq ^ (fr & 7)) * 8;        // swizzled chunk slot, kk=0
  const int c1 = ((4 + fq) ^ (fr & 7)) * 8;  // kk=1

  const int tq = t >> 3;
  const int scol = ((t & 7) ^ (tq & 7)) * 8;
  const u16* Asrc = A  + (size_t)(m0 + tq) * K + scol;
  const int rowB = (tq & 31) + ((t >> 8) << 6);
  const u16* Bsrc = Wt + (size_t)(n0 + rowB) * K + scol;
  const int dA = t * 8;
  const int dB = 16384 + ((t >> 8) << 11) + t * 8;

#define SG_A(slot, src, h) do {                                               \
    const int _d = (slot) * 32768 + (h) * 4096 + dA;                          \
    const size_t _k = (size_t)(src) * 64 + (size_t)((h) * 64) * K;            \
    __builtin_amdgcn_global_load_lds(GADDR(Asrc + _k), LADDR(&lds[_d]), 16, 0, 0); \
    __builtin_amdgcn_global_load_lds(GADDR(Asrc + _k + (size_t)128 * K),      \
                                     LADDR(&lds[_d + 8192]), 16, 0, 0);       \
  } while (0)
#define SG_B(slot, src, h) do {                                               \
    const int _d = (slot) * 32768 + (h) * 2048 + dB;                          \
    const size_t _k = (size_t)(src) * 64 + (size_t)((h) * 32) * K;            \
    __builtin_amdgcn_global_load_lds(GADDR(Bsrc + _k), LADDR(&lds[_d]), 16, 0, 0); \
    __builtin_amdgcn_global_load_lds(GADDR(Bsrc + _k + (size_t)128 * K),      \
                                     LADDR(&lds[_d + 8192]), 16, 0, 0);       \
  } while (0)

  f32x4 acc[8][4];
#pragma unroll
  for (int a = 0; a < 8; ++a)
#pragma unroll
    for (int b = 0; b < 4; ++b) acc[a][b] = (f32x4){0.f, 0.f, 0.f, 0.f};

  const int NT = K >> 6;               // BK=64 tiles; NT is even (8 or 32)
  SG_A(0, 0, 0); SG_A(0, 0, 1); SG_B(0, 0, 0); SG_B(0, 0, 1);
  SG_A(1, 1, 0); SG_B(1, 1, 0); SG_B(1, 1, 1);
  asm volatile("s_waitcnt vmcnt(6)" ::: "memory");
  __builtin_amdgcn_s_barrier();

#define TILE_BODY(S, SLOT, NSLOT, P0_COND)                                    \
  {                                                                           \
    const u16* la = lds + (SLOT) * 32768;                                     \
    const u16* lb = la + 16384;                                               \
    bf16x8 af[8], bf0[4], bf1[4];                                             \
    _Pragma("unroll")                                                         \
    for (int mi = 0; mi < 4; ++mi) {                                          \
      const int r = (wr + mi * 16 + fr) * 64;                                 \
      af[mi * 2]     = *(const bf16x8*)&la[r + c0];                           \
      af[mi * 2 + 1] = *(const bf16x8*)&la[r + c1];                           \
    }                                                                         \
    _Pragma("unroll")                                                         \
    for (int ni = 0; ni < 2; ++ni) {                                          \
      const int r = (wc + ni * 16 + fr) * 64;                                 \
      bf0[ni * 2]     = *(const bf16x8*)&lb[r + c0];                          \
      bf0[ni * 2 + 1] = *(const bf16x8*)&lb[r + c1];                          \
    }                                                                         \
    if (P0_COND) SG_A(NSLOT, (S) + 1, 1);                                     \
    __builtin_amdgcn_s_barrier();                                             \
    asm volatile("s_waitcnt lgkmcnt(0)" ::: "memory");                        \
    __builtin_amdgcn_sched_barrier(0);                                        \
    __builtin_amdgcn_s_setprio(1);                                            \
    _Pragma("unroll")                                                         \
    for (int mi = 0; mi < 4; ++mi)                                            \
      _Pragma("unroll")                                                       \
      for (int ni = 0; ni < 2; ++ni) {                                        \
        acc[mi][ni] = __builtin_amdgcn_mfma_f32_16x16x32_bf16(                \
            af[mi * 2], bf0[ni * 2], acc[mi][ni], 0, 0, 0);                   \
        acc[mi][ni] = __builtin_amdgcn_mfma_f32_16x16x32_bf16(                \
            af[mi * 2 + 1], bf0[ni * 2 + 1], acc[mi][ni], 0, 0, 0);           \
      }                                                                       \
    __builtin_amdgcn_s_setprio(0);                                            \
    __builtin_amdgcn_s_barrier();                                             \
    _Pragma("unroll")                                                         \
    for (int ni = 0; ni < 2; ++ni) {                                          \
      const int r = (wc + 32 + ni * 16 + fr) * 64;                            \
      bf1[ni * 2]     = *(const bf16x8*)&lb[r + c0];                          \
      bf1[ni * 2 + 1] = *(const bf16x8*)&lb[r + c1];                          \
    }                                                                         \
    if ((S) + 2 < NT) SG_A(SLOT, (S) + 2, 0);                                 \
    __builtin_amdgcn_s_barrier();                                             \
    asm volatile("s_waitcnt lgkmcnt(0)" ::: "memory");                        \
    __builtin_amdgcn_sched_barrier(0);                                        \
    __builtin_amdgcn_s_setprio(1);                                            \
    _Pragma("unroll")                                                         \
    for (int mi = 0; mi < 4; ++mi)                                            \
      _Pragma("unroll")                                                       \
      for (int ni = 0; ni < 2; ++ni) {                                        \
        acc[mi][2 + ni] = __builtin_amdgcn_mfma_f32_16x16x32_bf16(            \
            af[mi * 2], bf1[ni * 2], acc[mi][2 + ni], 0, 0, 0);               \
        acc[mi][2 + ni] = __builtin_amdgcn_mfma_f32_16x16x32_bf16(            \
            af[mi * 2 + 1], bf1[ni * 2 + 1], acc[mi][2 + ni], 0, 0, 0);       \
      }                                                                       \
    __builtin_amdgcn_s_setprio(0);                                            \
    __builtin_amdgcn_s_barrier();                                             \
    _Pragma("unroll")                                                         \
    for (int mi = 0; mi < 4; ++mi) {                                          \
      const int r = (wr + 64 + mi * 16 + fr) * 64;                            \
      af[mi * 2]     = *(const bf16x8*)&la[r + c0];                           \
      af[mi * 2 + 1] = *(const bf16x8*)&la[r + c1];                           \
    }                                                                         \
    if ((S) + 2 < NT) SG_B(SLOT, (S) + 2, 0);                                 \
    __builtin_amdgcn_s_barrier();                                             \
    asm volatile("s_waitcnt lgkmcnt(0)" ::: "memory");                        \
    __builtin_amdgcn_sched_barrier(0);                                        \
    __builtin_amdgcn_s_setprio(1);                                            \
    _Pragma("unroll")                                                         \
    for (int mi = 0; mi < 4; ++mi)                                            \
      _Pragma("unroll")                                                       \
      for (int ni = 0; ni < 2; ++ni) {                                        \
        acc[4 + mi][ni] = __builtin_amdgcn_mfma_f32_16x16x32_bf16(            \
            af[mi * 2], bf0[ni * 2], acc[4 + mi][ni], 0, 0, 0);               \
        acc[4 + mi][ni] = __builtin_amdgcn_mfma_f32_16x16x32_bf16(            \
            af[mi * 2 + 1], bf0[ni * 2 + 1], acc[4 + mi][ni], 0, 0, 0);       \
      }                                                                       \
    __builtin_amdgcn_s_setprio(0);                                            \
    __builtin_amdgcn_s_barrier();                                             \
    if ((S) + 2 < NT) SG_B(SLOT, (S) + 2, 1);                                 \
    __builtin_amdgcn_s_barrier();                                             \
    __builtin_amdgcn_s_setprio(1);                                            \
    _Pragma("unroll")                                                         \
    for (int mi = 0; mi < 4; ++mi)                                            \
      _Pragma("unroll")                                                       \
      for (int ni = 0; ni < 2; ++ni) {                                        \
        acc[4 + mi][2 + ni] = __builtin_amdgcn_mfma_f32_16x16x32_bf16(        \
            af[mi * 2], bf1[ni * 2], acc[4 + mi][2 + ni], 0, 0, 0);           \
        acc[4 + mi][2 + ni] = __builtin_amdgcn_mfma_f32_16x16x32_bf16(        \
            af[mi * 2 + 1], bf1[ni * 2 + 1], acc[4 + mi][2 + ni], 0, 0, 0);   \
      }                                                                       \
    __builtin_amdgcn_s_setprio(0);                                            \
    if ((S) + 2 < NT) asm volatile("s_waitcnt vmcnt(6)" ::: "memory");        \
    else              asm volatile("s_waitcnt vmcnt(0)" ::: "memory");        \
    __builtin_amdgcn_s_barrier();                                             \
  }

  for (int s = 0; s < NT; s += 2) {
    TILE_BODY(s,     0, 1, true);
    TILE_BODY(s + 1, 1, 0, (s + 2 < NT));
  }
#undef TILE_BODY
#undef SG_A
#undef SG_B
  asm volatile("s_waitcnt vmcnt(0)" ::: "memory");  // drain before LDS reuse
  __syncthreads();

  // ---- epilogue: swizzled LDS stage -> coalesced stores ----
  float bv4[4];
#pragma unroll
  for (int ni = 0; ni < 4; ++ni) bv4[ni] = bias[n0 + wc + ni * 16 + fr];

  u16* uW = &lds[wid * 8192];
  u16* og = (u16*)outp;
#pragma unroll
  for (int mi = 0; mi < 8; ++mi) {
#pragma unroll
    for (int ni = 0; ni < 4; ++ni)
#pragma unroll
      for (int j = 0; j < 4; ++j) {
        float v = acc[mi][ni][j] + bv4[ni];
        if (MODE == 2) {               // tanh-approx GELU
          const float a2 = v * (1.5957691216f + 0.0713548162f * v * v);
          const float e = __expf(a2);
          v = v * (e * __builtin_amdgcn_rcpf(e + 1.0f));
        }
        uW[(fq * 4 + j) * 64 + ((ni ^ j ^ fq) & 3) * 16 + fr] = f2bf(v);
      }
#pragma unroll
    for (int p = 0; p < 2; ++p) {
      const int r = p * 8 + (lane >> 3);
      const int sg = (((lane & 7) >> 1) ^ (r & 3) ^ ((r >> 2) & 3)) & 3;
      u16x8 v8 = *(const u16x8*)&uW[r * 64 + sg * 16 + (lane & 1) * 8];
      const int row = m0 + wr + mi * 16 + r;
      *(u16x8*)&og[(size_t)row * N + n0 + wc + (lane & 7) * 8] = v8;
    }
  }
}

// ---------------------------------------------------------------------------
// Fused GEMM(128x512 tile) + residual + LayerNorm, bf16-residual edition.
// LNM 0: A=AO, resid=XW (window layout, row=rowg); writes X1B (token layout).
// LNM 1: A=HBUF, resid=X1B (row=rowg); writes d_out (f32).
// ---------------------------------------------------------------------------
template <int LNM>
__global__ __launch_bounds__(512, 1)
void gemm_ln(const u16* __restrict__ A, const u16* __restrict__ Wt,
             const float* __restrict__ bias, const u16* __restrict__ residb,
             const float* __restrict__ g, const float* __restrict__ bt,
             float* __restrict__ out1, u16* __restrict__ out1b, int K) {
  __shared__ u16 lds[61440];
  const int t = threadIdx.x;
  const int nwg = gridDim.x;
  const int wg = blockIdx.x;
  const int swz = (wg & 7) * (nwg >> 3) + (wg >> 3);   // nwg % 8 == 0
  const int m0 = swz * 128;

  const int lane = t & 63;
  const int wid = t >> 6;
  const int wc = wid * 64;
  const int fr = lane & 15, fq = lane >> 4;
  const int rx = (fr >> 1) & 3;

  const int srow = t >> 2;             // 0..127
  const int schk = ((t & 3) ^ ((srow >> 1) & 3)) * 8;
  const u16* Ag = A  + (size_t)(m0 + srow) * K + schk;
  const u16* Bg = Wt + (size_t)srow * K + schk;

#define GLSTAGE_A(tile, buf)                                                  \
    __builtin_amdgcn_global_load_lds(GADDR(Ag + (size_t)(tile) * 32),         \
        LADDR(&lds[(buf) * 20480 + t * 8]), 16, 0, 0)
#define GLSTAGE_B(tile, buf, p)                                               \
    __builtin_amdgcn_global_load_lds(                                         \
        GADDR(Bg + (size_t)(p) * 128 * K + (size_t)(tile) * 32),              \
        LADDR(&lds[(buf) * 20480 + 4096 + (p) * 4096 + t * 8]), 16, 0, 0)

  f32x4 acc[8][4];
#pragma unroll
  for (int a = 0; a < 8; ++a)
#pragma unroll
    for (int b = 0; b < 4; ++b) acc[a][b] = (f32x4){0.f, 0.f, 0.f, 0.f};

  const int NT = K >> 5;
  GLSTAGE_A(0, 0);
  GLSTAGE_B(0, 0, 0); GLSTAGE_B(0, 0, 1); GLSTAGE_B(0, 0, 2); GLSTAGE_B(0, 0, 3);
  GLSTAGE_A(1, 1);
  GLSTAGE_B(1, 1, 0); GLSTAGE_B(1, 1, 1); GLSTAGE_B(1, 1, 2); GLSTAGE_B(1, 1, 3);

  int cur = 0;
  for (int u = 0; u < NT; ++u) {
    if (u + 1 < NT) asm volatile("s_waitcnt vmcnt(5)" ::: "memory");
    else            asm volatile("s_waitcnt vmcnt(0)" ::: "memory");
    __builtin_amdgcn_s_barrier();

    const u16* lb = lds + cur * 20480;
    const int stg = (cur == 0) ? 2 : cur - 1;   // (cur+2)%3
    bf16x8 bfr[4], af0[4], af1[4];
#pragma unroll
    for (int ni = 0; ni < 4; ++ni)
      bfr[ni] = *(const bf16x8*)&lb[4096 + (wc + ni * 16 + fr) * 32 + (fq ^ rx) * 8];
#pragma unroll
    for (int mi = 0; mi < 4; ++mi)
      af0[mi] = *(const bf16x8*)&lb[(mi * 16 + fr) * 32 + (fq ^ rx) * 8];
    if (u + 2 < NT) {
      GLSTAGE_A(u + 2, stg);
      GLSTAGE_B(u + 2, stg, 0); GLSTAGE_B(u + 2, stg, 1);
    }
#pragma unroll
    for (int mi = 0; mi < 4; ++mi)
      af1[mi] = *(const bf16x8*)&lb[((4 + mi) * 16 + fr) * 32 + (fq ^ rx) * 8];
    if (u + 2 < NT) {
      GLSTAGE_B(u + 2, stg, 2); GLSTAGE_B(u + 2, stg, 3);
    }

    __builtin_amdgcn_s_setprio(1);
#pragma unroll
    for (int mi = 0; mi < 4; ++mi)
#pragma unroll
      for (int ni = 0; ni < 4; ++ni)
        acc[mi][ni] = __builtin_amdgcn_mfma_f32_16x16x32_bf16(
            af0[mi], bfr[ni], acc[mi][ni], 0, 0, 0);
    __builtin_amdgcn_s_setprio(0);
    __builtin_amdgcn_s_setprio(1);
#pragma unroll
    for (int mi = 0; mi < 4; ++mi)
#pragma unroll
      for (int ni = 0; ni < 4; ++ni)
        acc[4 + mi][ni] = __builtin_amdgcn_mfma_f32_16x16x32_bf16(
            af1[mi], bfr[ni], acc[4 + mi][ni], 0, 0, 0);
    __builtin_amdgcn_s_setprio(0);
    cur = (cur == 2) ? 0 : cur + 1;
  }
#undef GLSTAGE_A
#undef GLSTAGE_B

  // ---- LN epilogue: per mi-group of 16 rows ----
  __syncthreads();
  float bv4[4];
#pragma unroll
  for (int ni = 0; ni < 4; ++ni) bv4[ni] = bias[wc + ni * 16 + fr];
  float4 ga = ((const float4*)g)[lane * 2];
  float4 gb = ((const float4*)g)[lane * 2 + 1];
  float4 ba = ((const float4*)bt)[lane * 2];
  float4 bb = ((const float4*)bt)[lane * 2 + 1];
  const float gv[8] = {ga.x, ga.y, ga.z, ga.w, gb.x, gb.y, gb.z, gb.w};
  const float bv[8] = {ba.x, ba.y, ba.z, ba.w, bb.x, bb.y, bb.z, bb.w};
  float* fLN = (float*)lds;            // 16 x 512 f32, chunk-swizzled

#pragma unroll
  for (int mi = 0; mi < 8; ++mi) {
#pragma unroll
    for (int ni = 0; ni < 4; ++ni)
#pragma unroll
      for (int j = 0; j < 4; ++j) {
        const int ch = ((wid * 4 + ni) ^ (j << 2) ^ fq) & 31;   // bank-spread
        fLN[(fq * 4 + j) * 512 + ch * 16 + fr] = acc[mi][ni][j] + bv4[ni];
      }
    __syncthreads();
    // wave `wid` normalizes rows 2*wid, 2*wid+1
#pragma unroll
    for (int rr = 0; rr < 2; ++rr) {
      const int r = wid * 2 + rr;
      const int gci = lane >> 1;
      const int ch = (gci ^ ((r & 3) << 2) ^ (r >> 2)) & 31;
      const int base = r * 512 + ch * 16 + (lane & 1) * 8;
      f32x4 va = *(const f32x4*)&fLN[base];
      f32x4 vb = *(const f32x4*)&fLN[base + 4];
      float v[8] = {va[0], va[1], va[2], va[3], vb[0], vb[1], vb[2], vb[3]};
      float s = 0.f, s2 = 0.f;
#pragma unroll
      for (int e = 0; e < 8; ++e) { s += v[e]; s2 = fmaf(v[e], v[e], s2); }
#pragma unroll
      for (int off = 32; off; off >>= 1) {
        s += __shfl_xor(s, off); s2 += __shfl_xor(s2, off);
      }
      const float mu = s * (1.f / 512.f);
      const float rs = rsqrtf(s2 * (1.f / 512.f) - mu * mu + 1e-5f);
      const int rowg = m0 + mi * 16 + r;
      u16x8 rv8 = *(const u16x8*)(residb + (size_t)rowg * 512 + lane * 8);
      float rv[8];
#pragma unroll
      for (int e = 0; e < 8; ++e) rv[e] = bf2f(rv8[e]);
      float o[8];
#pragma unroll
      for (int e = 0; e < 8; ++e)
        o[e] = rv[e] + (v[e] - mu) * rs * gv[e] + bv[e];
      if (LNM == 0) {                  // window-reverse + roll(+4,+4)
        const int w = rowg >> 6, i = rowg & 63;
        const int b = w >> 6, win = w & 63;
        const int hs = (((win >> 3) << 3) + (i >> 3) + 4) & 63;
        const int ws2 = (((win & 7) << 3) + (i & 7) + 4) & 63;
        const size_t token = ((size_t)b << 12) + hs * 64 + ws2;
        u16x8 ob;
#pragma unroll
        for (int e = 0; e < 8; ++e) ob[e] = f2bf(o[e]);
        *(u16x8*)(out1b + token * 512 + lane * 8) = ob;
      } else {
        float* op = out1 + (size_t)rowg * 512 + lane * 8;
        ((f32x4*)op)[0] = (f32x4){o[0], o[1], o[2], o[3]};
        ((f32x4*)op)[1] = (f32x4){o[4], o[5], o[6], o[7]};
      }
    }
    __syncthreads();
  }
}

// ---------------------------------------------------------------------------
// Windowed cosine attention, MFMA version. One wave per (window, head).
// ---------------------------------------------------------------------------
__global__ __launch_bounds__(64)
void attn_kernel(const u16* __restrict__ qkv, const float* __restrict__ bias2,
                 const float* __restrict__ tau, u16* __restrict__ ao) {
  const int h = blockIdx.x;
  const int w = blockIdx.y;
  const int lane = threadIdx.x;
  const int fr = lane & 15, fq = lane >> 4;

  __shared__ u16 sh[7424];

  const size_t rowb = ((size_t)w * 64 + lane) * 1536 + (size_t)h * 32;
  u16x8 q8[4], k8[4], v8[4];
#pragma unroll
  for (int u = 0; u < 4; ++u) {
    q8[u] = ((const u16x8*)(qkv + rowb))[u];
    k8[u] = ((const u16x8*)(qkv + rowb + 512))[u];
    v8[u] = ((const u16x8*)(qkv + rowb + 1024))[u];
  }
  float qv[32], kv[32];
  float qn = 0.f, kn = 0.f;
#pragma unroll
  for (int d = 0; d < 32; ++d) {
    qv[d] = bf2f(q8[d >> 3][d & 7]); qn = fmaf(qv[d], qv[d], qn);
    kv[d] = bf2f(k8[d >> 3][d & 7]); kn = fmaf(kv[d], kv[d], kn);
  }
  const float itau = 1.0f / fmaxf(tau[h], 0.01f);
  const float qs = rsqrtf(fmaxf(qn, 1e-24f)) * itau;
  const float ks = rsqrtf(fmaxf(kn, 1e-24f));
#pragma unroll
  for (int u = 0; u < 4; ++u) {
    u16x8 qo, ko;
#pragma unroll
    for (int e = 0; e < 8; ++e) {
      qo[e] = f2bf(qv[u * 8 + e] * qs);
      ko[e] = f2bf(kv[u * 8 + e] * ks);
    }
    *(u16x8*)&sh[lane * 40 + u * 8] = qo;
    *(u16x8*)&sh[2560 + lane * 40 + u * 8] = ko;
  }
#pragma unroll
  for (int d = 0; d < 32; ++d)
    sh[5120 + d * 72 + lane] = v8[d >> 3][d & 7];   // V^T, raw bf16
  __syncthreads();

  f32x4 acc[4][4];
  const float4* b2 = (const float4*)bias2 + (size_t)h * 1024 + lane;
#pragma unroll
  for (int mi = 0; mi < 4; ++mi)
#pragma unroll
    for (int ni = 0; ni < 4; ++ni) {
      float4 bv = b2[(mi * 4 + ni) * 64];
      acc[mi][ni] = (f32x4){bv.x, bv.y, bv.z, bv.w};
    }
  const int win = w & 63, wh = win >> 3, ww = win & 7;
  if (wh == 7 || ww == 7) {
    int labc[4];
#pragma unroll
    for (int ni = 0; ni < 4; ++ni) {
      const int c = ni * 16 + fr;
      labc[ni] = ((wh == 7) ? (((c >> 3) < 4) ? 1 : 2) : 0) * 3
               + ((ww == 7) ? (((c & 7) < 4) ? 1 : 2) : 0);
    }
#pragma unroll
    for (int mi = 0; mi < 4; ++mi)
#pragma unroll
      for (int j = 0; j < 4; ++j) {
        const int r = mi * 16 + fq * 4 + j;
        const int lr = ((wh == 7) ? (((r >> 3) < 4) ? 1 : 2) : 0) * 3
                     + ((ww == 7) ? (((r & 7) < 4) ? 1 : 2) : 0);
#pragma unroll
        for (int ni = 0; ni < 4; ++ni)
          if (lr != labc[ni]) acc[mi][ni][j] -= 100.f;
      }
  }

  {
    bf16x8 af[4], bf[4];
#pragma unroll
    for (int mi = 0; mi < 4; ++mi)
      af[mi] = *(const bf16x8*)&sh[(mi * 16 + fr) * 40 + fq * 8];
#pragma unroll
    for (int ni = 0; ni < 4; ++ni)
      bf[ni] = *(const bf16x8*)&sh[2560 + (ni * 16 + fr) * 40 + fq * 8];
#pragma unroll
    for (int mi = 0; mi < 4; ++mi)
#pragma unroll
      for (int ni = 0; ni < 4; ++ni)
        acc[mi][ni] = __builtin_amdgcn_mfma_f32_16x16x32_bf16(
            af[mi], bf[ni], acc[mi][ni], 0, 0, 0);
  }

  float lrec[4][4];
#pragma unroll
  for (int mi = 0; mi < 4; ++mi) {
#pragma unroll
    for (int j = 0; j < 4; ++j) {
      float m4 = fmaxf(fmaxf(acc[mi][0][j], acc[mi][1][j]),
                       fmaxf(acc[mi][2][j], acc[mi][3][j]));
#pragma unroll
      for (int mk = 1; mk < 16; mk <<= 1) m4 = fmaxf(m4, __shfl_xor(m4, mk));
      float e0 = __expf(acc[mi][0][j] - m4);
      float e1 = __expf(acc[mi][1][j] - m4);
      float e2 = __expf(acc[mi][2][j] - m4);
      float e3 = __expf(acc[mi][3][j] - m4);
      float s4 = (e0 + e1) + (e2 + e3);
#pragma unroll
      for (int mk = 1; mk < 16; mk <<= 1) s4 += __shfl_xor(s4, mk);
      lrec[mi][j] = __builtin_amdgcn_rcpf(s4);
      const int r = mi * 16 + fq * 4 + j;
      sh[r * 72 +  0 + fr] = f2bf(e0);
      sh[r * 72 + 16 + fr] = f2bf(e1);
      sh[r * 72 + 32 + fr] = f2bf(e2);
      sh[r * 72 + 48 + fr] = f2bf(e3);
    }
  }
  __syncthreads();

  f32x4 acc2[4][2];
#pragma unroll
  for (int mi = 0; mi < 4; ++mi)
#pragma unroll
    for (int n2 = 0; n2 < 2; ++n2) acc2[mi][n2] = (f32x4){0.f, 0.f, 0.f, 0.f};
#pragma unroll
  for (int kk = 0; kk < 2; ++kk) {
    bf16x8 pf[4], vf[2];
#pragma unroll
    for (int mi = 0; mi < 4; ++mi)
      pf[mi] = *(const bf16x8*)&sh[(mi * 16 + fr) * 72 + kk * 32 + fq * 8];
#pragma unroll
    for (int n2 = 0; n2 < 2; ++n2)
      vf[n2] = *(const bf16x8*)&sh[5120 + (n2 * 16 + fr) * 72 + kk * 32 + fq * 8];
#pragma unroll
    for (int mi = 0; mi < 4; ++mi)
#pragma unroll
      for (int n2 = 0; n2 < 2; ++n2)
        acc2[mi][n2] = __builtin_amdgcn_mfma_f32_16x16x32_bf16(
            pf[mi], vf[n2], acc2[mi][n2], 0, 0, 0);
  }

  u16* op = ao + ((size_t)w * 64) * 512 + (size_t)h * 32;
#pragma unroll
  for (int mi = 0; mi < 4; ++mi)
#pragma unroll
    for (int j = 0; j < 4; ++j) {
      const int r = mi * 16 + fq * 4 + j;
      const float sc = lrec[mi][j];
      op[(size_t)r * 512 +  0 + fr] = f2bf(acc2[mi][0][j] * sc);
      op[(size_t)r * 512 + 16 + fr] = f2bf(acc2[mi][1][j] * sc);
    }
}

// ---------------------------------------------------------------------------
extern "C" void kernel_launch(void* const* d_in, const int* in_sizes, int n_in,
                              void* d_out, int out_size, void* d_ws, size_t ws_size,
                              hipStream_t stream) {
  const float* x      = (const float*)d_in[0];
  const float* qkv_w  = (const float*)d_in[1];
  const float* qkv_b  = (const float*)d_in[2];
  const float* proj_w = (const float*)d_in[3];
  const float* proj_b = (const float*)d_in[4];
  const float* tau    = (const float*)d_in[5];
  const float* mw1    = (const float*)d_in[6];
  const float* mb1    = (const float*)d_in[7];
  const float* mw2    = (const float*)d_in[8];
  const float* mb2    = (const float*)d_in[9];
  const float* n1g    = (const float*)d_in[10];
  const float* n1b    = (const float*)d_in[11];
  const float* n2g    = (const float*)d_in[12];
  const float* n2b    = (const float*)d_in[13];
  const float* mlp_w1 = (const float*)d_in[14];
  const float* mlp_b1 = (const float*)d_in[15];
  const float* mlp_w2 = (const float*)d_in[16];
  const float* mlp_b2 = (const float*)d_in[17];

  char* ws = (char*)d_ws;
  u16*   WQKVT  = (u16*)  (ws + 0);
  u16*   WPROJT = (u16*)  (ws + 1572864);
  u16*   WM1T   = (u16*)  (ws + 2097152);
  u16*   WM2T   = (u16*)  (ws + 4194304);
  float* BIASB  = (float*)(ws + 6291456);
  float* BIAS2  = (float*)(ws + 6553600);
  const size_t CH0 = 8388608;

  // Tightened footprint: 7168 B/row = 29,360,128 B per batch (was 32 MiB --
  // the old layout carried a dead 1024 B/row gap). Lower threshold may allow
  // CB=32 (single chunk) on a ~1 GiB workspace.
  int CB = 32;
  while (CB > 1 && CH0 + (size_t)CB * 29360128ull > ws_size) CB >>= 1;
  const int NCH = 32 / CB;
  const size_t Mc = (size_t)CB * 4096;

  u16*   XW   = (u16*)  (ws + CH0);                     // Mc*1024
  u16*   QKV  = (u16*)  (ws + CH0 + Mc * 1024);         // Mc*4096 (alias HBUF)
  u16*   HBUF = QKV;
  u16*   AO   = (u16*)  (ws + CH0 + Mc * 5120);         // Mc*1024
  u16*   X1B  = (u16*)  (ws + CH0 + Mc * 6144);         // Mc*1024

  wt_kernel<<<(512 * 1536 + 255) / 256, 256, 0, stream>>>(qkv_w, WQKVT, 512, 1536);
  wt_kernel<<<(512 * 512 + 255) / 256, 256, 0, stream>>>(proj_w, WPROJT, 512, 512);
  wt_kernel<<<(512 * 2048 + 255) / 256, 256, 0, stream>>>(mlp_w1, WM1T, 512, 2048);
  wt_kernel<<<(2048 * 512 + 255) / 256, 256, 0, stream>>>(mlp_w2, WM2T, 2048, 512);
  bias_kernel<<<4096, 64, 0, stream>>>(mw1, mb1, mw2, mb2, BIASB);
  bias2_kernel<<<256, 64, 0, stream>>>(BIASB, BIAS2);

  const unsigned MB = (unsigned)(Mc / 256);    // 256-row tiles per chunk
  const unsigned LB = (unsigned)(Mc / 128);    // 128-row tiles per chunk

  for (int c = 0; c < NCH; ++c) {
    const float* xc = x + (size_t)c * Mc * 512;
    float* oc = (float*)d_out + (size_t)c * Mc * 512;

    partition_kernel<<<(unsigned)Mc, 128, 0, stream>>>(xc, XW);
    gemm8<0><<<dim3(6, MB), 512, 0, stream>>>(XW, WQKVT, qkv_b, QKV,
                                              (int)Mc, 1536, 512);
    attn_kernel<<<dim3(16, CB * 64), 64, 0, stream>>>(QKV, BIAS2, tau, AO);
    gemm_ln<0><<<LB, 512, 0, stream>>>(AO, WPROJT, proj_b, XW, n1g, n1b,
                                       nullptr, X1B, 512);
    gemm8<2><<<dim3(8, MB), 512, 0, stream>>>(X1B, WM1T, mlp_b1, HBUF,
                                              (int)Mc, 2048, 512);
    gemm_ln<1><<<LB, 512, 0, stream>>>(HBUF, WM2T, mlp_b2, X1B, n2g, n2b,
                                       oc, nullptr, 2048);
  }
}